// Round 10
// baseline (1013.581 us; speedup 1.0000x reference)
//
#include <hip/hip_runtime.h>
#include <hip/hip_bf16.h>
#include <math.h>

#define B_   128
#define L_   1024
#define E_   8
#define K_   3

typedef float f32x4 __attribute__((ext_vector_type(4)));
typedef short s8v  __attribute__((ext_vector_type(8)));
typedef unsigned short u16x8 __attribute__((ext_vector_type(8)));

__device__ inline ushort f2bf(float v) {
  union { float f; unsigned u; } x; x.f = v;
  unsigned r = (x.u + 0x7fffu + ((x.u >> 16) & 1u)) >> 16;
  return (ushort)r;
}
__device__ inline float bf2f(ushort h) {
  union { unsigned u; float f; } x; x.u = ((unsigned)h) << 16;
  return x.f;
}

// async global->LDS DMA, 16B/lane; dest linear in granule index.
__device__ __forceinline__ void gload_lds16(const ushort* g, ushort* l) {
  __builtin_amdgcn_global_load_lds(
      (const __attribute__((address_space(1))) unsigned int*)g,
      (__attribute__((address_space(3))) unsigned int*)l, 16, 0, 0);
}

// ---------------------------------------------------------------------------
// conv1: x[128,1,1024] -> h[128,16,1024] (ReLU) + pooled[128,16]
// ---------------------------------------------------------------------------
__global__ __launch_bounds__(256) void conv1_k(
    const float* __restrict__ x, const float* __restrict__ w,
    const float* __restrict__ bias, float* __restrict__ h,
    float* __restrict__ pooled)
{
  const int b = blockIdx.x;
  const int t = threadIdx.x;
  __shared__ float xs[1026];
  __shared__ float wsm[48];
  __shared__ float bs[16];
  __shared__ float red[4][16];

  for (int i = t; i < 1024; i += 256) xs[i + 1] = x[(size_t)b * 1024 + i];
  if (t == 0) { xs[0] = 0.f; xs[1025] = 0.f; }
  if (t < 48) wsm[t] = w[t];
  if (t < 16) bs[t] = bias[t];
  __syncthreads();

  float ps[16];
#pragma unroll
  for (int c = 0; c < 16; ++c) ps[c] = 0.f;

  for (int li = 0; li < 4; ++li) {
    const int l = t + li * 256;
    const float xm = xs[l], x0 = xs[l + 1], xp = xs[l + 2];
#pragma unroll
    for (int co = 0; co < 16; ++co) {
      float v = fmaf(wsm[co * 3 + 0], xm,
                fmaf(wsm[co * 3 + 1], x0,
                fmaf(wsm[co * 3 + 2], xp, bs[co])));
      v = fmaxf(v, 0.f);
      h[((size_t)b * 16 + co) * 1024 + l] = v;
      ps[co] += v;
    }
  }
#pragma unroll
  for (int co = 0; co < 16; ++co) {
    float v = ps[co];
    for (int off = 32; off > 0; off >>= 1) v += __shfl_down(v, off, 64);
    ps[co] = v;
  }
  const int wid = t >> 6, lane = t & 63;
  if (lane == 0) {
#pragma unroll
    for (int co = 0; co < 16; ++co) red[wid][co] = ps[co];
  }
  __syncthreads();
  if (t < 16) pooled[(size_t)b * 16 + t] =
      (red[0][t] + red[1][t] + red[2][t] + red[3][t]) * (1.f / 1024.f);
}

// ---------------------------------------------------------------------------
// router: pooled -> top3 gates + cv^2
// ---------------------------------------------------------------------------
__global__ void router_k(const float* __restrict__ pooled,
                         const float* __restrict__ rw,
                         const float* __restrict__ rb,
                         float* __restrict__ pair_g, int* __restrict__ pair_e,
                         float* __restrict__ cv2_out)
{
  const int b = threadIdx.x;  // 0..127
  __shared__ float pl[128][8];
  __shared__ float mp[8];

  float pv[16];
#pragma unroll
  for (int i = 0; i < 16; ++i) pv[i] = pooled[(size_t)b * 16 + i];

  float lg[8];
#pragma unroll
  for (int e = 0; e < 8; ++e) {
    float s = rb[e];
#pragma unroll
    for (int i = 0; i < 16; ++i) s = fmaf(pv[i], rw[e * 16 + i], s);
    lg[e] = s;
  }
  float mx = lg[0];
#pragma unroll
  for (int e = 1; e < 8; ++e) mx = fmaxf(mx, lg[e]);
  float pr[8]; float sum = 0.f;
#pragma unroll
  for (int e = 0; e < 8; ++e) { pr[e] = expf(lg[e] - mx); sum += pr[e]; }
  const float inv = 1.f / sum;
#pragma unroll
  for (int e = 0; e < 8; ++e) { pr[e] *= inv; pl[b][e] = pr[e]; }

  bool used[8] = {false,false,false,false,false,false,false,false};
  float tg[3]; int ti[3];
  for (int k = 0; k < 3; ++k) {
    float best = -1.f; int bi = 0;
#pragma unroll
    for (int e = 0; e < 8; ++e)
      if (!used[e] && pr[e] > best) { best = pr[e]; bi = e; }
    used[bi] = true; tg[k] = best; ti[k] = bi;
  }
  const float ts = 1.f / (tg[0] + tg[1] + tg[2]);
  for (int k = 0; k < 3; ++k) {
    pair_g[b * 3 + k] = tg[k] * ts;
    pair_e[b * 3 + k] = ti[k];
  }
  __syncthreads();
  if (b < 8) {
    float s = 0.f;
    for (int i = 0; i < 128; ++i) s += pl[i][b];
    mp[b] = s * (1.f / 128.f);
  }
  __syncthreads();
  if (b == 0) {
    float m = 0.f;
    for (int e = 0; e < 8; ++e) m += mp[e];
    m *= (1.f / 8.f);
    float v = 0.f;
    for (int e = 0; e < 8; ++e) { float d = mp[e] - m; v += d * d; }
    v *= (1.f / 7.f);
    const float cv = sqrtf(v) / (m + 1e-10f);
    cv2_out[0] = cv * cv;
  }
}

// ---------------------------------------------------------------------------
// Vector conv (e1, e2 only)
// ---------------------------------------------------------------------------
template <int CI, int CO, int LIN, bool POOL, int CIC, int CO_T, int CO_R,
          int IN_DIV>
__global__ __launch_bounds__(256) void convR_k(
    const float* __restrict__ in, const float* __restrict__ w,
    const float* __restrict__ bias, float* __restrict__ out,
    const int* __restrict__ pe)
{
  constexpr int CQ  = CO_T / CO_R;
  constexpr int LQ  = 256 / CQ;
  constexpr int L_T = LQ * 4;
  constexpr int LOUT = POOL ? (LIN / 2) : LIN;
  constexpr int RS  = L_T + 8;
  constexpr int CG  = CO_R / 4;

  const int p  = blockIdx.x;
  const int cb = blockIdx.y * CO_T;
  const int l0 = blockIdx.z * L_T;
  const int e  = pe ? pe[p] : 0;
  const float* inp = in + (size_t)(p / IN_DIV) * CI * LIN;
  const float* wp  = w + (size_t)e * CO * CI * 3;

  __shared__ float in_s[CIC * RS];
  __shared__ float w_s[CIC * 3 * CO_T];

  const int t  = threadIdx.x;
  const int cq = t / LQ;
  const int lq = t % LQ;

  float acc[CO_R][4];
#pragma unroll
  for (int c = 0; c < CO_R; ++c)
#pragma unroll
    for (int l = 0; l < 4; ++l) acc[c][l] = 0.f;

  for (int c0 = 0; c0 < CI; c0 += CIC) {
    for (int idx = t; idx < CIC * (L_T + 2); idx += 256) {
      const int ci = idx / (L_T + 2);
      const int j  = idx - ci * (L_T + 2);
      const int gl = l0 + j - 1;
      in_s[ci * RS + j] =
          (gl >= 0 && gl < LIN) ? inp[(size_t)(c0 + ci) * LIN + gl] : 0.f;
    }
    for (int i = t; i < CIC * CO_T; i += 256) {
      const int co = i % CO_T;
      const int ci = i / CO_T;
      const float* wsrc = wp + ((size_t)(cb + co) * CI + (c0 + ci)) * 3;
      const float w0 = wsrc[0], w1 = wsrc[1], w2 = wsrc[2];
      w_s[(ci * 3 + 0) * CO_T + co] = w0;
      w_s[(ci * 3 + 1) * CO_T + co] = w1;
      w_s[(ci * 3 + 2) * CO_T + co] = w2;
    }
    __syncthreads();
#pragma unroll 4
    for (int ci = 0; ci < CIC; ++ci) {
      const float* row = &in_s[ci * RS + lq * 4];
      const float4 xa = *reinterpret_cast<const float4*>(row);
      const float2 xb = *reinterpret_cast<const float2*>(row + 4);
      const float xv[6] = {xa.x, xa.y, xa.z, xa.w, xb.x, xb.y};
      const float* wrow = &w_s[ci * 3 * CO_T + cq * CO_R];
#pragma unroll
      for (int k = 0; k < 3; ++k) {
#pragma unroll
        for (int cg = 0; cg < CG; ++cg) {
          const float4 wv =
              *reinterpret_cast<const float4*>(&wrow[k * CO_T + cg * 4]);
          const float wq[4] = {wv.x, wv.y, wv.z, wv.w};
#pragma unroll
          for (int c = 0; c < 4; ++c)
#pragma unroll
            for (int l = 0; l < 4; ++l)
              acc[cg * 4 + c][l] = fmaf(wq[c], xv[l + k], acc[cg * 4 + c][l]);
        }
      }
    }
    __syncthreads();
  }

#pragma unroll
  for (int c = 0; c < CO_R; ++c) {
    const int co = cb + cq * CO_R + c;
    const float bv = bias[(size_t)e * CO + co];
    const float v0 = acc[c][0] + bv, v1 = acc[c][1] + bv;
    const float v2 = acc[c][2] + bv, v3 = acc[c][3] + bv;
    float* op = out + ((size_t)p * CO + co) * LOUT;
    if (POOL) {
      const int lo = (l0 >> 1) + lq * 2;
      float2 r;
      r.x = fmaxf(fmaxf(v0, v1), 0.f);
      r.y = fmaxf(fmaxf(v2, v3), 0.f);
      *reinterpret_cast<float2*>(&op[lo]) = r;
    } else {
      const int l = l0 + lq * 4;
      *reinterpret_cast<float4*>(&op[l]) = make_float4(v0, v1, v2, v3);
    }
  }
}

// ---------------------------------------------------------------------------
// Weight prep: w fp32 [E][CO][CI][3] -> hi/lo bf16 [E][3][CI/32][CO][32]
// ---------------------------------------------------------------------------
__global__ void wprep_k(const float* __restrict__ w, ushort* __restrict__ oh,
                        ushort* __restrict__ ol, int E, int CO, int CI,
                        int total)
{
  const int idx = blockIdx.x * 256 + threadIdx.x;
  if (idx >= total) return;
  const int KC = CI >> 5;
  const int j = idx & 31;
  int r = idx >> 5;
  const int co = r % CO; r /= CO;
  const int kc = r % KC; r /= KC;
  const int tp = r % 3;
  const int e  = r / 3;
  const float v = w[(((size_t)e * CO + co) * CI + (kc * 32 + j)) * 3 + tp];
  const ushort hi = f2bf(v);
  oh[idx] = hi;
  ol[idx] = f2bf(v - bf2f(hi));
}

// ---------------------------------------------------------------------------
// t0: e2 out fp32 [P][32][512] -> xt3 hi/lo bf16 [P][514][32] (halo rows 0)
// ---------------------------------------------------------------------------
__global__ __launch_bounds__(256) void t0_k(const float* __restrict__ in,
                                            ushort* __restrict__ oh,
                                            ushort* __restrict__ ol)
{
  __shared__ float tile[32][33];
  const int p  = blockIdx.x;
  const int l0 = blockIdx.y * 32;
  const int tx = threadIdx.x & 31;
  const int ty = threadIdx.x >> 5;

#pragma unroll
  for (int i = 0; i < 4; ++i) {
    const int ci = ty + i * 8;
    tile[ci][tx] = in[(size_t)p * 16384 + (size_t)ci * 512 + l0 + tx];
  }
  __syncthreads();
#pragma unroll
  for (int i = 0; i < 4; ++i) {
    const int l = l0 + ty + i * 8;
    const float v = tile[tx][ty + i * 8];
    const size_t o = ((size_t)p * 514 + 1 + l) * 32 + tx;
    const ushort hi = f2bf(v);
    oh[o] = hi;
    ol[o] = f2bf(v - bf2f(hi));
  }
  if (blockIdx.y == 0 && threadIdx.x < 32) {
    const size_t o0 = (size_t)p * 514 * 32 + threadIdx.x;
    const size_t o1 = ((size_t)p * 514 + 513) * 32 + threadIdx.x;
    oh[o0] = 0; ol[o0] = 0; oh[o1] = 0; ol[o1] = 0;
  }
}

// ---------------------------------------------------------------------------
// T2: comb fp32 [128][128][512] -> xtF hi/lo bf16 [128][130][512] (halos)
// ---------------------------------------------------------------------------
__global__ __launch_bounds__(256) void t2_k(const float* __restrict__ comb,
                                            ushort* __restrict__ oh,
                                            ushort* __restrict__ ol)
{
  const size_t o4 = ((size_t)blockIdx.x * 256 + threadIdx.x) * 4;
  const int p = (int)(o4 / 66560);
  const int rem = (int)(o4 - (size_t)p * 66560);
  const int r = rem >> 9;
  const int c = rem & 511;
  ushort4 h4, l4;
  if (r == 0 || r == 129) {
    h4 = make_ushort4(0, 0, 0, 0);
    l4 = make_ushort4(0, 0, 0, 0);
  } else {
    const float4 v =
        *reinterpret_cast<const float4*>(&comb[((size_t)p * 128 + (r - 1)) * 512 + c]);
    h4.x = f2bf(v.x); l4.x = f2bf(v.x - bf2f(h4.x));
    h4.y = f2bf(v.y); l4.y = f2bf(v.y - bf2f(h4.y));
    h4.z = f2bf(v.z); l4.z = f2bf(v.z - bf2f(h4.z));
    h4.w = f2bf(v.w); l4.w = f2bf(v.w - bf2f(h4.w));
  }
  *reinterpret_cast<ushort4*>(&oh[o4]) = h4;
  *reinterpret_cast<ushort4*>(&ol[o4]) = l4;
}

// ---------------------------------------------------------------------------
// MFMA conv1d (k=3, pad=1), split-bf16 (hi/lo), 16x16x32 bf16 MFMA.
// X: [NP][L+2][CI] hi/lo bf16 staged via global_load_lds (LDS = X only,
// 16.6 KB). W: [E][3][CI/32][CO][32] read DIRECTLY global->VGPR in the MFMA
// loop (coalesced 1KB/wave per fragment; same addresses across blocks ->
// L1/L2-resident). Removes 24/36 per-wave LDS reads + 24KB LDS.
// D: col=lane&15, row=(lane>>4)*4+reg (HW-verified layout).
// OMODE 0: plain conv -> bf16 hi/lo out [NP][L+2][CO] (halo zeroed)
// OMODE 1: relu+pool, gate applied -> y6[pair][L/2][CO] fp32 (single write)
// OMODE 2: relu+pool, fp32 transposed [NP][CO][L/2]
// OMODE 3: relu+pool -> bf16 hi/lo out [NP][L/2+2][CO] (halo zeroed)
// ---------------------------------------------------------------------------
template <int CI, int CO, int L, int OMODE>
__global__ __launch_bounds__(256) void convM_k(
    const ushort* __restrict__ xh, const ushort* __restrict__ xl,
    const ushort* __restrict__ wh, const ushort* __restrict__ wl,
    const float* __restrict__ bias,
    ushort* __restrict__ oh, ushort* __restrict__ ol,
    float* __restrict__ of,
    const int* __restrict__ pe, const float* __restrict__ pg,
    int pair0, int kpass)
{
  constexpr int KC = CI / 32;
  const int bx = blockIdx.x;
  const int cb = blockIdx.y * 64;
  const int lz = blockIdx.z * 128;

  int e = 0; float gate = 1.f;
  if (OMODE != 2) e = pe[pair0 + bx];
  if (OMODE == 1) gate = pg[pair0 + bx];
  const int lp = bx;

  __shared__ ushort xs[2][130][32];
  ushort* xsf = &xs[0][0][0];

  const int t = threadIdx.x;
  const int lane = t & 63;
  const int wv = t >> 6;
  const int l16 = lane & 15;
  const int kb8 = (lane >> 4) * 8;

  f32x4 acc[2][4];
#pragma unroll
  for (int a = 0; a < 2; ++a)
#pragma unroll
    for (int b = 0; b < 4; ++b) acc[a][b] = (f32x4){0.f, 0.f, 0.f, 0.f};

  const size_t xbase = ((size_t)lp * (L + 2) + lz) * CI;

  for (int kc = 0; kc < KC; ++kc) {
    const int c0 = kc * 32;
    // X: 1040 granules (2 planes x 130 rows x 4), dest linear = xsf + g*8
#pragma unroll
    for (int it = 0; it < 5; ++it) {
      const int g = it * 256 + t;
      if (g < 1040) {
        const int pl = g >= 520;
        const int r = g - pl * 520;
        const int row = r >> 2;
        const int c16 = r & 3;
        const ushort* src =
            (pl ? xl : xh) + xbase + (size_t)row * CI + c0 + c16 * 8;
        gload_lds16(src, xsf + (size_t)g * 8);
      }
    }
    __syncthreads();  // drains vmcnt (X staging) before use

#pragma unroll
    for (int tp = 0; tp < 3; ++tp) {
      const int ar = wv * 32 + l16 + tp;
      s8v a00 = *reinterpret_cast<const s8v*>(&xs[0][ar][kb8]);
      s8v a01 = *reinterpret_cast<const s8v*>(&xs[0][ar + 16][kb8]);
      s8v a10 = *reinterpret_cast<const s8v*>(&xs[1][ar][kb8]);
      s8v a11 = *reinterpret_cast<const s8v*>(&xs[1][ar + 16][kb8]);
      const size_t wbase =
          ((((size_t)e * 3 + tp) * KC + kc) * CO + cb) * 32;
#pragma unroll
      for (int cs = 0; cs < 4; ++cs) {
        const size_t wo = wbase + (size_t)(cs * 16 + l16) * 32 + kb8;
        s8v bh = *reinterpret_cast<const s8v*>(&wh[wo]);
        s8v bl = *reinterpret_cast<const s8v*>(&wl[wo]);
        acc[0][cs] = __builtin_amdgcn_mfma_f32_16x16x32_bf16(a00, bh, acc[0][cs], 0, 0, 0);
        acc[0][cs] = __builtin_amdgcn_mfma_f32_16x16x32_bf16(a00, bl, acc[0][cs], 0, 0, 0);
        acc[0][cs] = __builtin_amdgcn_mfma_f32_16x16x32_bf16(a10, bh, acc[0][cs], 0, 0, 0);
        acc[1][cs] = __builtin_amdgcn_mfma_f32_16x16x32_bf16(a01, bh, acc[1][cs], 0, 0, 0);
        acc[1][cs] = __builtin_amdgcn_mfma_f32_16x16x32_bf16(a01, bl, acc[1][cs], 0, 0, 0);
        acc[1][cs] = __builtin_amdgcn_mfma_f32_16x16x32_bf16(a11, bh, acc[1][cs], 0, 0, 0);
      }
    }
    __syncthreads();
  }

  float bv[4];
#pragma unroll
  for (int cs = 0; cs < 4; ++cs)
    bv[cs] = bias[(size_t)e * CO + cb + cs * 16 + l16];

  if (OMODE == 0) {
#pragma unroll
    for (int ls = 0; ls < 2; ++ls)
#pragma unroll
      for (int cs = 0; cs < 4; ++cs)
#pragma unroll
        for (int r = 0; r < 4; ++r) {
          const int l = lz + wv * 32 + ls * 16 + (lane >> 4) * 4 + r;
          const float v = acc[ls][cs][r] + bv[cs];
          const size_t o = ((size_t)lp * (L + 2) + 1 + l) * CO + cb + cs * 16 + l16;
          const ushort hi = f2bf(v);
          oh[o] = hi;
          ol[o] = f2bf(v - bf2f(hi));
        }
    if (blockIdx.z == 0 && t < 64) {
      const size_t o0 = (size_t)lp * (L + 2) * CO + cb + t;
      const size_t o1 = ((size_t)lp * (L + 2) + (L + 1)) * CO + cb + t;
      oh[o0] = 0; ol[o0] = 0; oh[o1] = 0; ol[o1] = 0;
    }
  } else if (OMODE == 3) {
#pragma unroll
    for (int ls = 0; ls < 2; ++ls)
#pragma unroll
      for (int cs = 0; cs < 4; ++cs)
#pragma unroll
        for (int r = 0; r < 4; r += 2) {
          const float v0 = acc[ls][cs][r] + bv[cs];
          const float v1 = acc[ls][cs][r + 1] + bv[cs];
          const float m = fmaxf(fmaxf(v0, v1), 0.f);
          const int lpp = (lz + wv * 32 + ls * 16 + (lane >> 4) * 4 + r) >> 1;
          const size_t o = ((size_t)lp * (L / 2 + 2) + 1 + lpp) * CO + cb + cs * 16 + l16;
          const ushort hi = f2bf(m);
          oh[o] = hi;
          ol[o] = f2bf(m - bf2f(hi));
        }
    if (blockIdx.z == 0 && t < 64) {
      const size_t o0 = (size_t)lp * (L / 2 + 2) * CO + cb + t;
      const size_t o1 = ((size_t)lp * (L / 2 + 2) + (L / 2 + 1)) * CO + cb + t;
      oh[o0] = 0; ol[o0] = 0; oh[o1] = 0; ol[o1] = 0;
    }
  } else if (OMODE == 1) {
#pragma unroll
    for (int ls = 0; ls < 2; ++ls)
#pragma unroll
      for (int cs = 0; cs < 4; ++cs)
#pragma unroll
        for (int r = 0; r < 4; r += 2) {
          const float v0 = acc[ls][cs][r] + bv[cs];
          const float v1 = acc[ls][cs][r + 1] + bv[cs];
          const float m = fmaxf(fmaxf(v0, v1), 0.f);
          const int lpp = (lz + wv * 32 + ls * 16 + (lane >> 4) * 4 + r) >> 1;
          const int co = cb + cs * 16 + l16;
          of[((size_t)bx * (L / 2) + lpp) * CO + co] = gate * m;
        }
  } else {
#pragma unroll
    for (int ls = 0; ls < 2; ++ls)
#pragma unroll
      for (int cs = 0; cs < 4; ++cs)
#pragma unroll
        for (int r = 0; r < 4; r += 2) {
          const float v0 = acc[ls][cs][r] + bv[cs];
          const float v1 = acc[ls][cs][r + 1] + bv[cs];
          const float m = fmaxf(fmaxf(v0, v1), 0.f);
          const int lpp = (lz + wv * 32 + ls * 16 + (lane >> 4) * 4 + r) >> 1;
          const int co = cb + cs * 16 + l16;
          const size_t o = ((size_t)lp * CO + co) * (L / 2) + lpp;
          of[o] = m;
        }
  }
}

// ---------------------------------------------------------------------------
// combine3: comb[b] = sum_k y6[b*3+k]
// ---------------------------------------------------------------------------
__global__ void combine3_k(const float4* __restrict__ y6,
                           float4* __restrict__ outc, int total4)
{
  const int idx = blockIdx.x * 256 + threadIdx.x;
  if (idx >= total4) return;
  const int b = idx >> 14;
  const int r = idx & 16383;
  const float4 a = y6[(size_t)(b * 3 + 0) * 16384 + r];
  const float4 c = y6[(size_t)(b * 3 + 1) * 16384 + r];
  const float4 d = y6[(size_t)(b * 3 + 2) * 16384 + r];
  float4 o;
  o.x = a.x + c.x + d.x;
  o.y = a.y + c.y + d.y;
  o.z = a.z + c.z + d.z;
  o.w = a.w + c.w + d.w;
  outc[idx] = o;
}

// ---------------------------------------------------------------------------
// fc1 MFMA split-bf16 GEMM (unchanged from round 8)
// ---------------------------------------------------------------------------
__global__ __launch_bounds__(256) void fc1M_k(const float* __restrict__ X,
                                              const float* __restrict__ W,
                                              float* __restrict__ part)
{
  __shared__ ushort xs[2][128][32];
  __shared__ ushort wsm[2][64][32];
  const int t = threadIdx.x;
  const int lane = t & 63;
  const int wv = t >> 6;
  const int l16 = lane & 15;
  const int kb8 = (lane >> 4) * 8;
  const int ot = blockIdx.x * 64;
  const size_t k0g = (size_t)blockIdx.y * 512;

  f32x4 acc[2][4];
#pragma unroll
  for (int a = 0; a < 2; ++a)
#pragma unroll
    for (int b = 0; b < 4; ++b) acc[a][b] = (f32x4){0.f, 0.f, 0.f, 0.f};

  const int xrow = t >> 1;
  const int xcol = (t & 1) * 16;
  const int wco  = t >> 2;
  const int wk   = (t & 3) * 8;

  for (int it = 0; it < 16; ++it) {
    const size_t k0 = k0g + it * 32;
    {
      const float* src = X + (size_t)xrow * 65536 + k0 + xcol;
      float v[16];
#pragma unroll
      for (int q = 0; q < 4; ++q)
        *reinterpret_cast<float4*>(&v[q * 4]) =
            *reinterpret_cast<const float4*>(src + q * 4);
#pragma unroll
      for (int q = 0; q < 2; ++q) {
        u16x8 hv, lv;
#pragma unroll
        for (int j = 0; j < 8; ++j) {
          const float f = v[q * 8 + j];
          const ushort h = f2bf(f);
          hv[j] = h;
          lv[j] = f2bf(f - bf2f(h));
        }
        *reinterpret_cast<u16x8*>(&xs[0][xrow][xcol + q * 8]) = hv;
        *reinterpret_cast<u16x8*>(&xs[1][xrow][xcol + q * 8]) = lv;
      }
    }
    {
      const float* src = W + (size_t)(ot + wco) * 65536 + k0 + wk;
      float v[8];
      *reinterpret_cast<float4*>(&v[0]) = *reinterpret_cast<const float4*>(src);
      *reinterpret_cast<float4*>(&v[4]) = *reinterpret_cast<const float4*>(src + 4);
      u16x8 hv, lv;
#pragma unroll
      for (int j = 0; j < 8; ++j) {
        const ushort h = f2bf(v[j]);
        hv[j] = h;
        lv[j] = f2bf(v[j] - bf2f(h));
      }
      *reinterpret_cast<u16x8*>(&wsm[0][wco][wk]) = hv;
      *reinterpret_cast<u16x8*>(&wsm[1][wco][wk]) = lv;
    }
    __syncthreads();
#pragma unroll
    for (int ms = 0; ms < 2; ++ms) {
      const int ar = wv * 32 + ms * 16 + l16;
      s8v ah = *reinterpret_cast<const s8v*>(&xs[0][ar][kb8]);
      s8v al = *reinterpret_cast<const s8v*>(&xs[1][ar][kb8]);
#pragma unroll
      for (int cs = 0; cs < 4; ++cs) {
        const int brow = cs * 16 + l16;
        s8v bh = *reinterpret_cast<const s8v*>(&wsm[0][brow][kb8]);
        s8v bl = *reinterpret_cast<const s8v*>(&wsm[1][brow][kb8]);
        acc[ms][cs] = __builtin_amdgcn_mfma_f32_16x16x32_bf16(ah, bh, acc[ms][cs], 0, 0, 0);
        acc[ms][cs] = __builtin_amdgcn_mfma_f32_16x16x32_bf16(ah, bl, acc[ms][cs], 0, 0, 0);
        acc[ms][cs] = __builtin_amdgcn_mfma_f32_16x16x32_bf16(al, bh, acc[ms][cs], 0, 0, 0);
      }
    }
    __syncthreads();
  }

#pragma unroll
  for (int ms = 0; ms < 2; ++ms)
#pragma unroll
    for (int cs = 0; cs < 4; ++cs)
#pragma unroll
      for (int r = 0; r < 4; ++r) {
        const int row = wv * 32 + ms * 16 + (lane >> 4) * 4 + r;
        const int col = ot + cs * 16 + l16;
        part[((size_t)blockIdx.y * 128 + row) * 256 + col] = acc[ms][cs][r];
      }
}

__global__ void fc1red_k(const float* __restrict__ part,
                         const float* __restrict__ b1, float* __restrict__ o1)
{
  const int idx = blockIdx.x * 256 + threadIdx.x;
  if (idx < 32768) {
    float s = 0.f;
#pragma unroll 8
    for (int z = 0; z < 128; ++z) s += part[(size_t)z * 32768 + idx];
    o1[idx] = fmaxf(s + b1[idx & 255], 0.f);
  }
}

__global__ void fc2_k(const float* __restrict__ o1, const float* __restrict__ w2,
                      const float* __restrict__ b2, float* __restrict__ out)
{
  const int b = blockIdx.x;
  const int lane = threadIdx.x;
  float acc[5] = {0.f, 0.f, 0.f, 0.f, 0.f};
  for (int i = lane; i < 256; i += 64) {
    const float xv = o1[(size_t)b * 256 + i];
#pragma unroll
    for (int o = 0; o < 5; ++o) acc[o] = fmaf(xv, w2[o * 256 + i], acc[o]);
  }
#pragma unroll
  for (int o = 0; o < 5; ++o) {
    for (int off = 32; off > 0; off >>= 1)
      acc[o] += __shfl_down(acc[o], off, 64);
  }
  if (lane == 0) {
#pragma unroll
    for (int o = 0; o < 5; ++o) out[b * 5 + o] = acc[o] + b2[o];
  }
}

// ---------------------------------------------------------------------------
// launcher
// ---------------------------------------------------------------------------
extern "C" void kernel_launch(void* const* d_in, const int* in_sizes, int n_in,
                              void* d_out, int out_size, void* d_ws,
                              size_t ws_size, hipStream_t stream)
{
  const float* x   = (const float*)d_in[0];
  const float* c1w = (const float*)d_in[1];
  const float* c1b = (const float*)d_in[2];
  const float* ew[6];
  const float* eb[6];
  for (int j = 0; j < 6; ++j) {
    ew[j] = (const float*)d_in[3 + 2 * j];
    eb[j] = (const float*)d_in[4 + 2 * j];
  }
  const float* rw  = (const float*)d_in[15];
  const float* rb  = (const float*)d_in[16];
  const float* c2w = (const float*)d_in[17];
  const float* c2b = (const float*)d_in[18];
  const float* f1w = (const float*)d_in[19];
  const float* f1b = (const float*)d_in[20];
  const float* f2w = (const float*)d_in[21];
  const float* f2b = (const float*)d_in[22];
  float* out = (float*)d_out;

  const int chunkB = (ws_size >= 170000000ull) ? 32 : 16;
  const int chunkP = chunkB * 3;
  const int nchunk = 128 / chunkB;

  char* basep = (char*)d_ws;
  size_t off = 0;
  auto alloc = [&](size_t bytes) -> void* {
    off = (off + 255) & ~(size_t)255;
    void* r = basep + off;
    off += bytes;
    return r;
  };

  float* h      = (float*)alloc(2097152ull * 4);
  float* pooled = (float*)alloc(2048ull * 4);
  float* pairg  = (float*)alloc(384ull * 4);
  int*   paire  = (int*)  alloc(384ull * 4);
  float* fc1o   = (float*)alloc(32768ull * 4);
  float* comb   = (float*)alloc(8388608ull * 4);
  const size_t chunk_base = (off + 255) & ~(size_t)255;
  float*  bufA  = (float*)alloc((size_t)chunkP * 16384 * 4);
  float*  bufB  = (float*)alloc((size_t)chunkP * 16384 * 4);
  ushort* xt3h  = (ushort*)alloc((size_t)chunkP * 16448 * 2);
  ushort* xt3l  = (ushort*)alloc((size_t)chunkP * 16448 * 2);
  ushort* yE3h  = (ushort*)alloc((size_t)chunkP * 32896 * 2);
  ushort* yE3l  = (ushort*)alloc((size_t)chunkP * 32896 * 2);
  ushort* xt5h  = (ushort*)alloc((size_t)chunkP * 33024 * 2);
  ushort* xt5l  = (ushort*)alloc((size_t)chunkP * 33024 * 2);
  ushort* y5h   = (ushort*)alloc((size_t)chunkP * 66048 * 2);
  ushort* y5l   = (ushort*)alloc((size_t)chunkP * 66048 * 2);
  float*  y6    = (float*)alloc((size_t)chunkP * 65536 * 4);
  ushort* xtFh  = (ushort*)(basep + chunk_base);
  ushort* xtFl  = xtFh + 8519680ull;
  float* part   = (float*)(basep + chunk_base);
  ushort* wp3h  = (ushort*)alloc(49152ull * 2);
  ushort* wp3l  = (ushort*)alloc(49152ull * 2);
  ushort* wp4h  = (ushort*)alloc(196608ull * 2);
  ushort* wp4l  = (ushort*)alloc(196608ull * 2);
  ushort* wp5h  = (ushort*)alloc(786432ull * 2);
  ushort* wp5l  = (ushort*)alloc(786432ull * 2);
  ushort* wp6h  = (ushort*)alloc(3145728ull * 2);
  ushort* wp6l  = (ushort*)alloc(3145728ull * 2);
  ushort* wpFh  = (ushort*)alloc(1572864ull * 2);
  ushort* wpFl  = (ushort*)alloc(1572864ull * 2);

  conv1_k<<<128, 256, 0, stream>>>(x, c1w, c1b, h, pooled);
  router_k<<<1, 128, 0, stream>>>(pooled, rw, rb, pairg, paire, out + 640);

  wprep_k<<<(49152 + 255) / 256, 256, 0, stream>>>(ew[2], wp3h, wp3l, 8, 64, 32, 49152);
  wprep_k<<<(196608 + 255) / 256, 256, 0, stream>>>(ew[3], wp4h, wp4l, 8, 128, 64, 196608);
  wprep_k<<<(786432 + 255) / 256, 256, 0, stream>>>(ew[4], wp5h, wp5l, 8, 256, 128, 786432);
  wprep_k<<<(3145728 + 255) / 256, 256, 0, stream>>>(ew[5], wp6h, wp6l, 8, 512, 256, 3145728);
  wprep_k<<<(1572864 + 255) / 256, 256, 0, stream>>>(c2w, wpFh, wpFl, 1, 1024, 512, 1572864);

  for (int c = 0; c < nchunk; ++c) {
    const int b0 = c * chunkB;
    const int p0 = c * chunkP;
    convR_k<16, 16, 1024, false, 16, 16, 4, 3>
        <<<dim3(chunkP, 1, 4), 256, 0, stream>>>(
            h + (size_t)b0 * 16 * 1024, ew[0], eb[0], bufA, paire + p0);
    convR_k<16, 32, 1024, true, 16, 32, 8, 1>
        <<<dim3(chunkP, 1, 4), 256, 0, stream>>>(bufA, ew[1], eb[1], bufB,
                                                 paire + p0);
    t0_k<<<dim3(chunkP, 16), 256, 0, stream>>>(bufB, xt3h, xt3l);
    convM_k<32, 64, 512, 0>
        <<<dim3(chunkP, 1, 4), 256, 0, stream>>>(xt3h, xt3l, wp3h, wp3l, eb[2],
                                                 yE3h, yE3l, nullptr, paire,
                                                 nullptr, p0, 0);
    convM_k<64, 128, 512, 3>
        <<<dim3(chunkP, 2, 4), 256, 0, stream>>>(yE3h, yE3l, wp4h, wp4l, eb[3],
                                                 xt5h, xt5l, nullptr, paire,
                                                 nullptr, p0, 0);
    convM_k<128, 256, 256, 0>
        <<<dim3(chunkP, 4, 2), 256, 0, stream>>>(xt5h, xt5l, wp5h, wp5l, eb[4],
                                                 y5h, y5l, nullptr, paire,
                                                 nullptr, p0, 0);
    convM_k<256, 512, 256, 1>
        <<<dim3(chunkP, 8, 2), 256, 0, stream>>>(y5h, y5l, wp6h, wp6l, eb[5],
                                                 nullptr, nullptr, y6,
                                                 paire, pairg, p0, 0);
    combine3_k<<<(chunkB * 16384 + 255) / 256, 256, 0, stream>>>(
        (const float4*)y6, (float4*)(comb + (size_t)b0 * 65536),
        chunkB * 16384);
  }

  t2_k<<<8320, 256, 0, stream>>>(comb, xtFh, xtFl);
  convM_k<512, 1024, 128, 2>
      <<<dim3(128, 16, 1), 256, 0, stream>>>(xtFh, xtFl, wpFh, wpFl, c2b,
                                             nullptr, nullptr, comb, nullptr,
                                             nullptr, 0, 0);

  fc1M_k<<<dim3(4, 128), 256, 0, stream>>>(comb, f1w, part);
  fc1red_k<<<128, 256, 0, stream>>>(part, f1b, fc1o);
  fc2_k<<<128, 64, 0, stream>>>(fc1o, f2w, f2b, out);
}

// Round 11
// 665.272 us; speedup vs baseline: 1.5236x; 1.5236x over previous
//
#include <hip/hip_runtime.h>
#include <hip/hip_bf16.h>
#include <math.h>

#define B_   128
#define L_   1024
#define E_   8
#define K_   3

typedef float f32x4 __attribute__((ext_vector_type(4)));
typedef short s8v  __attribute__((ext_vector_type(8)));
typedef unsigned short u16x8 __attribute__((ext_vector_type(8)));

__device__ inline ushort f2bf(float v) {
  union { float f; unsigned u; } x; x.f = v;
  unsigned r = (x.u + 0x7fffu + ((x.u >> 16) & 1u)) >> 16;
  return (ushort)r;
}
__device__ inline float bf2f(ushort h) {
  union { unsigned u; float f; } x; x.u = ((unsigned)h) << 16;
  return x.f;
}

// async global->LDS DMA, 16B/lane; dest linear in granule index.
__device__ __forceinline__ void gload_lds16(const ushort* g, ushort* l) {
  __builtin_amdgcn_global_load_lds(
      (const __attribute__((address_space(1))) unsigned int*)g,
      (__attribute__((address_space(3))) unsigned int*)l, 16, 0, 0);
}

// ---------------------------------------------------------------------------
// conv1: x[128,1,1024] -> h[128,16,1024] (ReLU) + pooled[128,16]
// ---------------------------------------------------------------------------
__global__ __launch_bounds__(256) void conv1_k(
    const float* __restrict__ x, const float* __restrict__ w,
    const float* __restrict__ bias, float* __restrict__ h,
    float* __restrict__ pooled)
{
  const int b = blockIdx.x;
  const int t = threadIdx.x;
  __shared__ float xs[1026];
  __shared__ float wsm[48];
  __shared__ float bs[16];
  __shared__ float red[4][16];

  for (int i = t; i < 1024; i += 256) xs[i + 1] = x[(size_t)b * 1024 + i];
  if (t == 0) { xs[0] = 0.f; xs[1025] = 0.f; }
  if (t < 48) wsm[t] = w[t];
  if (t < 16) bs[t] = bias[t];
  __syncthreads();

  float ps[16];
#pragma unroll
  for (int c = 0; c < 16; ++c) ps[c] = 0.f;

  for (int li = 0; li < 4; ++li) {
    const int l = t + li * 256;
    const float xm = xs[l], x0 = xs[l + 1], xp = xs[l + 2];
#pragma unroll
    for (int co = 0; co < 16; ++co) {
      float v = fmaf(wsm[co * 3 + 0], xm,
                fmaf(wsm[co * 3 + 1], x0,
                fmaf(wsm[co * 3 + 2], xp, bs[co])));
      v = fmaxf(v, 0.f);
      h[((size_t)b * 16 + co) * 1024 + l] = v;
      ps[co] += v;
    }
  }
#pragma unroll
  for (int co = 0; co < 16; ++co) {
    float v = ps[co];
    for (int off = 32; off > 0; off >>= 1) v += __shfl_down(v, off, 64);
    ps[co] = v;
  }
  const int wid = t >> 6, lane = t & 63;
  if (lane == 0) {
#pragma unroll
    for (int co = 0; co < 16; ++co) red[wid][co] = ps[co];
  }
  __syncthreads();
  if (t < 16) pooled[(size_t)b * 16 + t] =
      (red[0][t] + red[1][t] + red[2][t] + red[3][t]) * (1.f / 1024.f);
}

// ---------------------------------------------------------------------------
// router: pooled -> top3 gates + cv^2
// ---------------------------------------------------------------------------
__global__ void router_k(const float* __restrict__ pooled,
                         const float* __restrict__ rw,
                         const float* __restrict__ rb,
                         float* __restrict__ pair_g, int* __restrict__ pair_e,
                         float* __restrict__ cv2_out)
{
  const int b = threadIdx.x;  // 0..127
  __shared__ float pl[128][8];
  __shared__ float mp[8];

  float pv[16];
#pragma unroll
  for (int i = 0; i < 16; ++i) pv[i] = pooled[(size_t)b * 16 + i];

  float lg[8];
#pragma unroll
  for (int e = 0; e < 8; ++e) {
    float s = rb[e];
#pragma unroll
    for (int i = 0; i < 16; ++i) s = fmaf(pv[i], rw[e * 16 + i], s);
    lg[e] = s;
  }
  float mx = lg[0];
#pragma unroll
  for (int e = 1; e < 8; ++e) mx = fmaxf(mx, lg[e]);
  float pr[8]; float sum = 0.f;
#pragma unroll
  for (int e = 0; e < 8; ++e) { pr[e] = expf(lg[e] - mx); sum += pr[e]; }
  const float inv = 1.f / sum;
#pragma unroll
  for (int e = 0; e < 8; ++e) { pr[e] *= inv; pl[b][e] = pr[e]; }

  bool used[8] = {false,false,false,false,false,false,false,false};
  float tg[3]; int ti[3];
  for (int k = 0; k < 3; ++k) {
    float best = -1.f; int bi = 0;
#pragma unroll
    for (int e = 0; e < 8; ++e)
      if (!used[e] && pr[e] > best) { best = pr[e]; bi = e; }
    used[bi] = true; tg[k] = best; ti[k] = bi;
  }
  const float ts = 1.f / (tg[0] + tg[1] + tg[2]);
  for (int k = 0; k < 3; ++k) {
    pair_g[b * 3 + k] = tg[k] * ts;
    pair_e[b * 3 + k] = ti[k];
  }
  __syncthreads();
  if (b < 8) {
    float s = 0.f;
    for (int i = 0; i < 128; ++i) s += pl[i][b];
    mp[b] = s * (1.f / 128.f);
  }
  __syncthreads();
  if (b == 0) {
    float m = 0.f;
    for (int e = 0; e < 8; ++e) m += mp[e];
    m *= (1.f / 8.f);
    float v = 0.f;
    for (int e = 0; e < 8; ++e) { float d = mp[e] - m; v += d * d; }
    v *= (1.f / 7.f);
    const float cv = sqrtf(v) / (m + 1e-10f);
    cv2_out[0] = cv * cv;
  }
}

// ---------------------------------------------------------------------------
// Vector conv (e1, e2 only)
// ---------------------------------------------------------------------------
template <int CI, int CO, int LIN, bool POOL, int CIC, int CO_T, int CO_R,
          int IN_DIV>
__global__ __launch_bounds__(256) void convR_k(
    const float* __restrict__ in, const float* __restrict__ w,
    const float* __restrict__ bias, float* __restrict__ out,
    const int* __restrict__ pe)
{
  constexpr int CQ  = CO_T / CO_R;
  constexpr int LQ  = 256 / CQ;
  constexpr int L_T = LQ * 4;
  constexpr int LOUT = POOL ? (LIN / 2) : LIN;
  constexpr int RS  = L_T + 8;
  constexpr int CG  = CO_R / 4;

  const int p  = blockIdx.x;
  const int cb = blockIdx.y * CO_T;
  const int l0 = blockIdx.z * L_T;
  const int e  = pe ? pe[p] : 0;
  const float* inp = in + (size_t)(p / IN_DIV) * CI * LIN;
  const float* wp  = w + (size_t)e * CO * CI * 3;

  __shared__ float in_s[CIC * RS];
  __shared__ float w_s[CIC * 3 * CO_T];

  const int t  = threadIdx.x;
  const int cq = t / LQ;
  const int lq = t % LQ;

  float acc[CO_R][4];
#pragma unroll
  for (int c = 0; c < CO_R; ++c)
#pragma unroll
    for (int l = 0; l < 4; ++l) acc[c][l] = 0.f;

  for (int c0 = 0; c0 < CI; c0 += CIC) {
    for (int idx = t; idx < CIC * (L_T + 2); idx += 256) {
      const int ci = idx / (L_T + 2);
      const int j  = idx - ci * (L_T + 2);
      const int gl = l0 + j - 1;
      in_s[ci * RS + j] =
          (gl >= 0 && gl < LIN) ? inp[(size_t)(c0 + ci) * LIN + gl] : 0.f;
    }
    for (int i = t; i < CIC * CO_T; i += 256) {
      const int co = i % CO_T;
      const int ci = i / CO_T;
      const float* wsrc = wp + ((size_t)(cb + co) * CI + (c0 + ci)) * 3;
      const float w0 = wsrc[0], w1 = wsrc[1], w2 = wsrc[2];
      w_s[(ci * 3 + 0) * CO_T + co] = w0;
      w_s[(ci * 3 + 1) * CO_T + co] = w1;
      w_s[(ci * 3 + 2) * CO_T + co] = w2;
    }
    __syncthreads();
#pragma unroll 4
    for (int ci = 0; ci < CIC; ++ci) {
      const float* row = &in_s[ci * RS + lq * 4];
      const float4 xa = *reinterpret_cast<const float4*>(row);
      const float2 xb = *reinterpret_cast<const float2*>(row + 4);
      const float xv[6] = {xa.x, xa.y, xa.z, xa.w, xb.x, xb.y};
      const float* wrow = &w_s[ci * 3 * CO_T + cq * CO_R];
#pragma unroll
      for (int k = 0; k < 3; ++k) {
#pragma unroll
        for (int cg = 0; cg < CG; ++cg) {
          const float4 wv =
              *reinterpret_cast<const float4*>(&wrow[k * CO_T + cg * 4]);
          const float wq[4] = {wv.x, wv.y, wv.z, wv.w};
#pragma unroll
          for (int c = 0; c < 4; ++c)
#pragma unroll
            for (int l = 0; l < 4; ++l)
              acc[cg * 4 + c][l] = fmaf(wq[c], xv[l + k], acc[cg * 4 + c][l]);
        }
      }
    }
    __syncthreads();
  }

#pragma unroll
  for (int c = 0; c < CO_R; ++c) {
    const int co = cb + cq * CO_R + c;
    const float bv = bias[(size_t)e * CO + co];
    const float v0 = acc[c][0] + bv, v1 = acc[c][1] + bv;
    const float v2 = acc[c][2] + bv, v3 = acc[c][3] + bv;
    float* op = out + ((size_t)p * CO + co) * LOUT;
    if (POOL) {
      const int lo = (l0 >> 1) + lq * 2;
      float2 r;
      r.x = fmaxf(fmaxf(v0, v1), 0.f);
      r.y = fmaxf(fmaxf(v2, v3), 0.f);
      *reinterpret_cast<float2*>(&op[lo]) = r;
    } else {
      const int l = l0 + lq * 4;
      *reinterpret_cast<float4*>(&op[l]) = make_float4(v0, v1, v2, v3);
    }
  }
}

// ---------------------------------------------------------------------------
// Weight prep: w fp32 [E][CO][CI][3] -> hi/lo bf16 [E][3][CI/32][CO][32]
// ---------------------------------------------------------------------------
__global__ void wprep_k(const float* __restrict__ w, ushort* __restrict__ oh,
                        ushort* __restrict__ ol, int E, int CO, int CI,
                        int total)
{
  const int idx = blockIdx.x * 256 + threadIdx.x;
  if (idx >= total) return;
  const int KC = CI >> 5;
  const int j = idx & 31;
  int r = idx >> 5;
  const int co = r % CO; r /= CO;
  const int kc = r % KC; r /= KC;
  const int tp = r % 3;
  const int e  = r / 3;
  const float v = w[(((size_t)e * CO + co) * CI + (kc * 32 + j)) * 3 + tp];
  const ushort hi = f2bf(v);
  oh[idx] = hi;
  ol[idx] = f2bf(v - bf2f(hi));
}

// ---------------------------------------------------------------------------
// t0: e2 out fp32 [P][32][512] -> xt3 hi/lo bf16 [P][514][32] (halo rows 0)
// ---------------------------------------------------------------------------
__global__ __launch_bounds__(256) void t0_k(const float* __restrict__ in,
                                            ushort* __restrict__ oh,
                                            ushort* __restrict__ ol)
{
  __shared__ float tile[32][33];
  const int p  = blockIdx.x;
  const int l0 = blockIdx.y * 32;
  const int tx = threadIdx.x & 31;
  const int ty = threadIdx.x >> 5;

#pragma unroll
  for (int i = 0; i < 4; ++i) {
    const int ci = ty + i * 8;
    tile[ci][tx] = in[(size_t)p * 16384 + (size_t)ci * 512 + l0 + tx];
  }
  __syncthreads();
#pragma unroll
  for (int i = 0; i < 4; ++i) {
    const int l = l0 + ty + i * 8;
    const float v = tile[tx][ty + i * 8];
    const size_t o = ((size_t)p * 514 + 1 + l) * 32 + tx;
    const ushort hi = f2bf(v);
    oh[o] = hi;
    ol[o] = f2bf(v - bf2f(hi));
  }
  if (blockIdx.y == 0 && threadIdx.x < 32) {
    const size_t o0 = (size_t)p * 514 * 32 + threadIdx.x;
    const size_t o1 = ((size_t)p * 514 + 513) * 32 + threadIdx.x;
    oh[o0] = 0; ol[o0] = 0; oh[o1] = 0; ol[o1] = 0;
  }
}

// ---------------------------------------------------------------------------
// T2: comb fp32 [128][128][512] -> xtF hi/lo bf16 [128][130][512] (halos)
// ---------------------------------------------------------------------------
__global__ __launch_bounds__(256) void t2_k(const float* __restrict__ comb,
                                            ushort* __restrict__ oh,
                                            ushort* __restrict__ ol)
{
  const size_t o4 = ((size_t)blockIdx.x * 256 + threadIdx.x) * 4;
  const int p = (int)(o4 / 66560);
  const int rem = (int)(o4 - (size_t)p * 66560);
  const int r = rem >> 9;
  const int c = rem & 511;
  ushort4 h4, l4;
  if (r == 0 || r == 129) {
    h4 = make_ushort4(0, 0, 0, 0);
    l4 = make_ushort4(0, 0, 0, 0);
  } else {
    const float4 v =
        *reinterpret_cast<const float4*>(&comb[((size_t)p * 128 + (r - 1)) * 512 + c]);
    h4.x = f2bf(v.x); l4.x = f2bf(v.x - bf2f(h4.x));
    h4.y = f2bf(v.y); l4.y = f2bf(v.y - bf2f(h4.y));
    h4.z = f2bf(v.z); l4.z = f2bf(v.z - bf2f(h4.z));
    h4.w = f2bf(v.w); l4.w = f2bf(v.w - bf2f(h4.w));
  }
  *reinterpret_cast<ushort4*>(&oh[o4]) = h4;
  *reinterpret_cast<ushort4*>(&ol[o4]) = l4;
}

// ---------------------------------------------------------------------------
// MFMA conv1d (k=3, pad=1), split-bf16 (hi/lo), 16x16x32 bf16 MFMA.
// X: [NP][L+2][CI] hi/lo bf16, W: [E][3][CI/32][CO][32]; BOTH staged to LDS
// via global_load_lds (round-8 proven structure; W-from-global regressed 2x
// in round 10 — MFMA operands must come from LDS).
// Block: 256 thr = 4 waves stacked in l. Block tile: 128 l x 64 co.
// D: col=lane&15, row=(lane>>4)*4+reg (HW-verified layout).
// OMODE 0: plain conv -> bf16 hi/lo out [NP][L+2][CO] (halo zeroed)
// OMODE 1: relu+pool; loops the 3 top-k pairs of batch (pair0+bx) INTERNALLY,
//          gacc += gate*relu(pool(conv)); single write to comb[b][L/2][CO]
// OMODE 2: relu+pool, fp32 transposed [NP][CO][L/2]
// OMODE 3: relu+pool -> bf16 hi/lo out [NP][L/2+2][CO] (halo zeroed)
// ---------------------------------------------------------------------------
template <int CI, int CO, int L, int OMODE>
__global__ __launch_bounds__(256) void convM_k(
    const ushort* __restrict__ xh, const ushort* __restrict__ xl,
    const ushort* __restrict__ wh, const ushort* __restrict__ wl,
    const float* __restrict__ bias,
    ushort* __restrict__ oh, ushort* __restrict__ ol,
    float* __restrict__ of,
    const int* __restrict__ pe, const float* __restrict__ pg,
    int pair0)
{
  constexpr int KC = CI / 32;
  constexpr int NK = (OMODE == 1) ? 3 : 1;
  const int bx = blockIdx.x;
  const int cb = blockIdx.y * 64;
  const int lz = blockIdx.z * 128;

  __shared__ ushort xs[2][130][32];
  __shared__ ushort wsm[2][3][64][32];
  ushort* xsf = &xs[0][0][0];
  ushort* wsf = &wsm[0][0][0][0];

  const int t = threadIdx.x;
  const int lane = t & 63;
  const int wv = t >> 6;
  const int l16 = lane & 15;
  const int kb8 = (lane >> 4) * 8;

  float gacc[2][4][2];
  if (OMODE == 1) {
#pragma unroll
    for (int a = 0; a < 2; ++a)
#pragma unroll
      for (int b = 0; b < 4; ++b) { gacc[a][b][0] = 0.f; gacc[a][b][1] = 0.f; }
  }

  f32x4 acc[2][4];
  int e = 0; float gate = 1.f; int lp = bx;
  float bv[4];

  for (int kp = 0; kp < NK; ++kp) {
    if (OMODE == 1) {
      const int gp = (pair0 + bx) * 3 + kp;  // pair0 = batch offset here
      e = pe[gp]; gate = pg[gp]; lp = bx * 3 + kp;
    } else if (OMODE == 2) { lp = bx; e = 0; }
    else { lp = bx; e = pe[pair0 + bx]; }

#pragma unroll
    for (int a = 0; a < 2; ++a)
#pragma unroll
      for (int b = 0; b < 4; ++b) acc[a][b] = (f32x4){0.f, 0.f, 0.f, 0.f};

    const size_t xbase = ((size_t)lp * (L + 2) + lz) * CI;

    for (int kc = 0; kc < KC; ++kc) {
      const int c0 = kc * 32;
      // X: 1040 granules (2 planes x 130 rows x 4), dest linear = xsf + g*8
#pragma unroll
      for (int it = 0; it < 5; ++it) {
        const int g = it * 256 + t;
        if (g < 1040) {
          const int pl = g >= 520;
          const int r = g - pl * 520;
          const int row = r >> 2;
          const int c16 = r & 3;
          const ushort* src =
              (pl ? xl : xh) + xbase + (size_t)row * CI + c0 + c16 * 8;
          gload_lds16(src, xsf + (size_t)g * 8);
        }
      }
      // W: 1536 granules (2 planes x 3 taps x 64 co x 4), dest = wsf + g*8
#pragma unroll
      for (int it = 0; it < 6; ++it) {
        const int g = it * 256 + t;
        const int pl = g >= 768;
        const int r = g - pl * 768;
        const int tp = r >> 8;
        const int rr = r & 255;
        const int co = rr >> 2;
        const int c16 = rr & 3;
        const ushort* src = (pl ? wl : wh) +
            ((((size_t)e * 3 + tp) * KC + kc) * CO + cb + co) * 32 + c16 * 8;
        gload_lds16(src, wsf + (size_t)g * 8);
      }
      __syncthreads();  // compiler drains vmcnt before s_barrier

#pragma unroll
      for (int tp = 0; tp < 3; ++tp) {
        const int ar = wv * 32 + l16 + tp;
        s8v a00 = *reinterpret_cast<const s8v*>(&xs[0][ar][kb8]);
        s8v a01 = *reinterpret_cast<const s8v*>(&xs[0][ar + 16][kb8]);
        s8v a10 = *reinterpret_cast<const s8v*>(&xs[1][ar][kb8]);
        s8v a11 = *reinterpret_cast<const s8v*>(&xs[1][ar + 16][kb8]);
#pragma unroll
        for (int cs = 0; cs < 4; ++cs) {
          const int brow = cs * 16 + l16;
          s8v bh = *reinterpret_cast<const s8v*>(&wsm[0][tp][brow][kb8]);
          s8v bl = *reinterpret_cast<const s8v*>(&wsm[1][tp][brow][kb8]);
          acc[0][cs] = __builtin_amdgcn_mfma_f32_16x16x32_bf16(a00, bh, acc[0][cs], 0, 0, 0);
          acc[0][cs] = __builtin_amdgcn_mfma_f32_16x16x32_bf16(a00, bl, acc[0][cs], 0, 0, 0);
          acc[0][cs] = __builtin_amdgcn_mfma_f32_16x16x32_bf16(a10, bh, acc[0][cs], 0, 0, 0);
          acc[1][cs] = __builtin_amdgcn_mfma_f32_16x16x32_bf16(a01, bh, acc[1][cs], 0, 0, 0);
          acc[1][cs] = __builtin_amdgcn_mfma_f32_16x16x32_bf16(a01, bl, acc[1][cs], 0, 0, 0);
          acc[1][cs] = __builtin_amdgcn_mfma_f32_16x16x32_bf16(a11, bh, acc[1][cs], 0, 0, 0);
        }
      }
      __syncthreads();
    }

#pragma unroll
    for (int cs = 0; cs < 4; ++cs)
      bv[cs] = bias[(size_t)e * CO + cb + cs * 16 + l16];

    if (OMODE == 1) {
#pragma unroll
      for (int ls = 0; ls < 2; ++ls)
#pragma unroll
        for (int cs = 0; cs < 4; ++cs)
#pragma unroll
          for (int q = 0; q < 2; ++q) {
            const float v0 = acc[ls][cs][q * 2] + bv[cs];
            const float v1 = acc[ls][cs][q * 2 + 1] + bv[cs];
            const float m = fmaxf(fmaxf(v0, v1), 0.f);
            gacc[ls][cs][q] += gate * m;
          }
    }
  }

  if (OMODE == 0) {
#pragma unroll
    for (int ls = 0; ls < 2; ++ls)
#pragma unroll
      for (int cs = 0; cs < 4; ++cs)
#pragma unroll
        for (int r = 0; r < 4; ++r) {
          const int l = lz + wv * 32 + ls * 16 + (lane >> 4) * 4 + r;
          const float v = acc[ls][cs][r] + bv[cs];
          const size_t o = ((size_t)lp * (L + 2) + 1 + l) * CO + cb + cs * 16 + l16;
          const ushort hi = f2bf(v);
          oh[o] = hi;
          ol[o] = f2bf(v - bf2f(hi));
        }
    if (blockIdx.z == 0 && t < 64) {
      const size_t o0 = (size_t)lp * (L + 2) * CO + cb + t;
      const size_t o1 = ((size_t)lp * (L + 2) + (L + 1)) * CO + cb + t;
      oh[o0] = 0; ol[o0] = 0; oh[o1] = 0; ol[o1] = 0;
    }
  } else if (OMODE == 3) {
#pragma unroll
    for (int ls = 0; ls < 2; ++ls)
#pragma unroll
      for (int cs = 0; cs < 4; ++cs)
#pragma unroll
        for (int r = 0; r < 4; r += 2) {
          const float v0 = acc[ls][cs][r] + bv[cs];
          const float v1 = acc[ls][cs][r + 1] + bv[cs];
          const float m = fmaxf(fmaxf(v0, v1), 0.f);
          const int lpp = (lz + wv * 32 + ls * 16 + (lane >> 4) * 4 + r) >> 1;
          const size_t o = ((size_t)lp * (L / 2 + 2) + 1 + lpp) * CO + cb + cs * 16 + l16;
          const ushort hi = f2bf(m);
          oh[o] = hi;
          ol[o] = f2bf(m - bf2f(hi));
        }
    if (blockIdx.z == 0 && t < 64) {
      const size_t o0 = (size_t)lp * (L / 2 + 2) * CO + cb + t;
      const size_t o1 = ((size_t)lp * (L / 2 + 2) + (L / 2 + 1)) * CO + cb + t;
      oh[o0] = 0; ol[o0] = 0; oh[o1] = 0; ol[o1] = 0;
    }
  } else if (OMODE == 1) {
#pragma unroll
    for (int ls = 0; ls < 2; ++ls)
#pragma unroll
      for (int cs = 0; cs < 4; ++cs)
#pragma unroll
        for (int q = 0; q < 2; ++q) {
          const int lpp = (lz + wv * 32 + ls * 16 + (lane >> 4) * 4 + q * 2) >> 1;
          const int co = cb + cs * 16 + l16;
          const size_t o = ((size_t)(pair0 + bx) * (L / 2) + lpp) * CO + co;
          of[o] = gacc[ls][cs][q];
        }
  } else {
#pragma unroll
    for (int ls = 0; ls < 2; ++ls)
#pragma unroll
      for (int cs = 0; cs < 4; ++cs)
#pragma unroll
        for (int r = 0; r < 4; r += 2) {
          const float v0 = acc[ls][cs][r] + bv[cs];
          const float v1 = acc[ls][cs][r + 1] + bv[cs];
          const float m = fmaxf(fmaxf(v0, v1), 0.f);
          const int lpp = (lz + wv * 32 + ls * 16 + (lane >> 4) * 4 + r) >> 1;
          const int co = cb + cs * 16 + l16;
          const size_t o = ((size_t)lp * CO + co) * (L / 2) + lpp;
          of[o] = m;
        }
  }
}

// ---------------------------------------------------------------------------
// fc1 MFMA split-bf16 GEMM (unchanged from round 8)
// ---------------------------------------------------------------------------
__global__ __launch_bounds__(256) void fc1M_k(const float* __restrict__ X,
                                              const float* __restrict__ W,
                                              float* __restrict__ part)
{
  __shared__ ushort xs[2][128][32];
  __shared__ ushort wsm[2][64][32];
  const int t = threadIdx.x;
  const int lane = t & 63;
  const int wv = t >> 6;
  const int l16 = lane & 15;
  const int kb8 = (lane >> 4) * 8;
  const int ot = blockIdx.x * 64;
  const size_t k0g = (size_t)blockIdx.y * 512;

  f32x4 acc[2][4];
#pragma unroll
  for (int a = 0; a < 2; ++a)
#pragma unroll
    for (int b = 0; b < 4; ++b) acc[a][b] = (f32x4){0.f, 0.f, 0.f, 0.f};

  const int xrow = t >> 1;
  const int xcol = (t & 1) * 16;
  const int wco  = t >> 2;
  const int wk   = (t & 3) * 8;

  for (int it = 0; it < 16; ++it) {
    const size_t k0 = k0g + it * 32;
    {
      const float* src = X + (size_t)xrow * 65536 + k0 + xcol;
      float v[16];
#pragma unroll
      for (int q = 0; q < 4; ++q)
        *reinterpret_cast<float4*>(&v[q * 4]) =
            *reinterpret_cast<const float4*>(src + q * 4);
#pragma unroll
      for (int q = 0; q < 2; ++q) {
        u16x8 hv, lv;
#pragma unroll
        for (int j = 0; j < 8; ++j) {
          const float f = v[q * 8 + j];
          const ushort h = f2bf(f);
          hv[j] = h;
          lv[j] = f2bf(f - bf2f(h));
        }
        *reinterpret_cast<u16x8*>(&xs[0][xrow][xcol + q * 8]) = hv;
        *reinterpret_cast<u16x8*>(&xs[1][xrow][xcol + q * 8]) = lv;
      }
    }
    {
      const float* src = W + (size_t)(ot + wco) * 65536 + k0 + wk;
      float v[8];
      *reinterpret_cast<float4*>(&v[0]) = *reinterpret_cast<const float4*>(src);
      *reinterpret_cast<float4*>(&v[4]) = *reinterpret_cast<const float4*>(src + 4);
      u16x8 hv, lv;
#pragma unroll
      for (int j = 0; j < 8; ++j) {
        const ushort h = f2bf(v[j]);
        hv[j] = h;
        lv[j] = f2bf(v[j] - bf2f(h));
      }
      *reinterpret_cast<u16x8*>(&wsm[0][wco][wk]) = hv;
      *reinterpret_cast<u16x8*>(&wsm[1][wco][wk]) = lv;
    }
    __syncthreads();
#pragma unroll
    for (int ms = 0; ms < 2; ++ms) {
      const int ar = wv * 32 + ms * 16 + l16;
      s8v ah = *reinterpret_cast<const s8v*>(&xs[0][ar][kb8]);
      s8v al = *reinterpret_cast<const s8v*>(&xs[1][ar][kb8]);
#pragma unroll
      for (int cs = 0; cs < 4; ++cs) {
        const int brow = cs * 16 + l16;
        s8v bh = *reinterpret_cast<const s8v*>(&wsm[0][brow][kb8]);
        s8v bl = *reinterpret_cast<const s8v*>(&wsm[1][brow][kb8]);
        acc[ms][cs] = __builtin_amdgcn_mfma_f32_16x16x32_bf16(ah, bh, acc[ms][cs], 0, 0, 0);
        acc[ms][cs] = __builtin_amdgcn_mfma_f32_16x16x32_bf16(ah, bl, acc[ms][cs], 0, 0, 0);
        acc[ms][cs] = __builtin_amdgcn_mfma_f32_16x16x32_bf16(al, bh, acc[ms][cs], 0, 0, 0);
      }
    }
    __syncthreads();
  }

#pragma unroll
  for (int ms = 0; ms < 2; ++ms)
#pragma unroll
    for (int cs = 0; cs < 4; ++cs)
#pragma unroll
      for (int r = 0; r < 4; ++r) {
        const int row = wv * 32 + ms * 16 + (lane >> 4) * 4 + r;
        const int col = ot + cs * 16 + l16;
        part[((size_t)blockIdx.y * 128 + row) * 256 + col] = acc[ms][cs][r];
      }
}

__global__ void fc1red_k(const float* __restrict__ part,
                         const float* __restrict__ b1, float* __restrict__ o1)
{
  const int idx = blockIdx.x * 256 + threadIdx.x;
  if (idx < 32768) {
    float s = 0.f;
#pragma unroll 8
    for (int z = 0; z < 128; ++z) s += part[(size_t)z * 32768 + idx];
    o1[idx] = fmaxf(s + b1[idx & 255], 0.f);
  }
}

__global__ void fc2_k(const float* __restrict__ o1, const float* __restrict__ w2,
                      const float* __restrict__ b2, float* __restrict__ out)
{
  const int b = blockIdx.x;
  const int lane = threadIdx.x;
  float acc[5] = {0.f, 0.f, 0.f, 0.f, 0.f};
  for (int i = lane; i < 256; i += 64) {
    const float xv = o1[(size_t)b * 256 + i];
#pragma unroll
    for (int o = 0; o < 5; ++o) acc[o] = fmaf(xv, w2[o * 256 + i], acc[o]);
  }
#pragma unroll
  for (int o = 0; o < 5; ++o) {
    for (int off = 32; off > 0; off >>= 1)
      acc[o] += __shfl_down(acc[o], off, 64);
  }
  if (lane == 0) {
#pragma unroll
    for (int o = 0; o < 5; ++o) out[b * 5 + o] = acc[o] + b2[o];
  }
}

// ---------------------------------------------------------------------------
// launcher
// ---------------------------------------------------------------------------
extern "C" void kernel_launch(void* const* d_in, const int* in_sizes, int n_in,
                              void* d_out, int out_size, void* d_ws,
                              size_t ws_size, hipStream_t stream)
{
  const float* x   = (const float*)d_in[0];
  const float* c1w = (const float*)d_in[1];
  const float* c1b = (const float*)d_in[2];
  const float* ew[6];
  const float* eb[6];
  for (int j = 0; j < 6; ++j) {
    ew[j] = (const float*)d_in[3 + 2 * j];
    eb[j] = (const float*)d_in[4 + 2 * j];
  }
  const float* rw  = (const float*)d_in[15];
  const float* rb  = (const float*)d_in[16];
  const float* c2w = (const float*)d_in[17];
  const float* c2b = (const float*)d_in[18];
  const float* f1w = (const float*)d_in[19];
  const float* f1b = (const float*)d_in[20];
  const float* f2w = (const float*)d_in[21];
  const float* f2b = (const float*)d_in[22];
  float* out = (float*)d_out;

  // chunkB=32 fits ~103 MB via ping-pong slot aliasing (known-good >=113 MB);
  // fall back to 16 if the workspace is unexpectedly small.
  const int chunkB = (ws_size >= 108000000ull) ? 32 : 16;
  const int chunkP = chunkB * 3;
  const int nchunk = 128 / chunkB;

  char* basep = (char*)d_ws;
  size_t off = 0;
  auto alloc = [&](size_t bytes) -> void* {
    off = (off + 255) & ~(size_t)255;
    void* r = basep + off;
    off += bytes;
    return r;
  };

  float* h      = (float*)alloc(2097152ull * 4);
  float* pooled = (float*)alloc(2048ull * 4);
  float* pairg  = (float*)alloc(384ull * 4);
  int*   paire  = (int*)  alloc(384ull * 4);
  float* fc1o   = (float*)alloc(32768ull * 4);
  float* comb   = (float*)alloc(8388608ull * 4);   // final conv out / fc1 X

  // ---- chunk region: two ping-pong slots ----
  // slotA: bufA (e1 out) -> xt3 (t0 out) -> xt5 (e4 out)
  // slotB: bufB (e2 out) -> yE3 (e3 out) -> y5 (e5 out)
  // lifetimes verified disjoint (producer of next always reads other slot).
  const size_t chunk_base = (off + 255) & ~(size_t)255;
  const size_t sA = (size_t)chunkP * 33024 * 2 * 2;  // xt5 hi+lo (largest)
  const size_t sB = (size_t)chunkP * 66048 * 2 * 2;  // y5 hi+lo (largest)
  const size_t creg = (sA + sB + 511 > 68157440ull) ? (sA + sB + 511)
                                                    : 68157440ull;  // >= xtF
  char* slotA = (char*)alloc(sA);
  char* slotB = (char*)alloc(sB);
  if (creg > sA + sB + 511) off = chunk_base + creg;  // reserve xtF room

  float*  bufA  = (float*)slotA;
  ushort* xt3h  = (ushort*)slotA;
  ushort* xt3l  = xt3h + (size_t)chunkP * 16448;
  ushort* xt5h  = (ushort*)slotA;
  ushort* xt5l  = xt5h + (size_t)chunkP * 33024;
  float*  bufB  = (float*)slotB;
  ushort* yE3h  = (ushort*)slotB;
  ushort* yE3l  = yE3h + (size_t)chunkP * 32896;
  ushort* y5h   = (ushort*)slotB;
  ushort* y5l   = y5h + (size_t)chunkP * 66048;

  // xtF [128][130][512] hi/lo (34.1 MB) and part [128][128][256] (16.8 MB)
  // alias the chunk region after all chunks complete.
  ushort* xtFh  = (ushort*)(basep + chunk_base);
  ushort* xtFl  = xtFh + 8519680ull;
  float*  part  = (float*)(basep + chunk_base);

  ushort* wp3h  = (ushort*)alloc(49152ull * 2);
  ushort* wp3l  = (ushort*)alloc(49152ull * 2);
  ushort* wp4h  = (ushort*)alloc(196608ull * 2);
  ushort* wp4l  = (ushort*)alloc(196608ull * 2);
  ushort* wp5h  = (ushort*)alloc(786432ull * 2);
  ushort* wp5l  = (ushort*)alloc(786432ull * 2);
  ushort* wp6h  = (ushort*)alloc(3145728ull * 2);
  ushort* wp6l  = (ushort*)alloc(3145728ull * 2);
  ushort* wpFh  = (ushort*)alloc(1572864ull * 2);
  ushort* wpFl  = (ushort*)alloc(1572864ull * 2);

  conv1_k<<<128, 256, 0, stream>>>(x, c1w, c1b, h, pooled);
  router_k<<<1, 128, 0, stream>>>(pooled, rw, rb, pairg, paire, out + 640);

  wprep_k<<<(49152 + 255) / 256, 256, 0, stream>>>(ew[2], wp3h, wp3l, 8, 64, 32, 49152);
  wprep_k<<<(196608 + 255) / 256, 256, 0, stream>>>(ew[3], wp4h, wp4l, 8, 128, 64, 196608);
  wprep_k<<<(786432 + 255) / 256, 256, 0, stream>>>(ew[4], wp5h, wp5l, 8, 256, 128, 786432);
  wprep_k<<<(3145728 + 255) / 256, 256, 0, stream>>>(ew[5], wp6h, wp6l, 8, 512, 256, 3145728);
  wprep_k<<<(1572864 + 255) / 256, 256, 0, stream>>>(c2w, wpFh, wpFl, 1, 1024, 512, 1572864);

  for (int c = 0; c < nchunk; ++c) {
    const int b0 = c * chunkB;
    const int p0 = c * chunkP;
    convR_k<16, 16, 1024, false, 16, 16, 4, 3>
        <<<dim3(chunkP, 1, 4), 256, 0, stream>>>(
            h + (size_t)b0 * 16 * 1024, ew[0], eb[0], bufA, paire + p0);
    convR_k<16, 32, 1024, true, 16, 32, 8, 1>
        <<<dim3(chunkP, 1, 4), 256, 0, stream>>>(bufA, ew[1], eb[1], bufB,
                                                 paire + p0);
    t0_k<<<dim3(chunkP, 16), 256, 0, stream>>>(bufB, xt3h, xt3l);
    convM_k<32, 64, 512, 0>
        <<<dim3(chunkP, 1, 4), 256, 0, stream>>>(xt3h, xt3l, wp3h, wp3l, eb[2],
                                                 yE3h, yE3l, nullptr, paire,
                                                 nullptr, p0);
    convM_k<64, 128, 512, 3>
        <<<dim3(chunkP, 2, 4), 256, 0, stream>>>(yE3h, yE3l, wp4h, wp4l, eb[3],
                                                 xt5h, xt5l, nullptr, paire,
                                                 nullptr, p0);
    convM_k<128, 256, 256, 0>
        <<<dim3(chunkP, 4, 2), 256, 0, stream>>>(xt5h, xt5l, wp5h, wp5l, eb[4],
                                                 y5h, y5l, nullptr, paire,
                                                 nullptr, p0);
    // e6: 3 top-k pairs looped in-kernel, gated sum -> comb[b0+bx] (pair0=b0)
    convM_k<256, 512, 256, 1>
        <<<dim3(chunkB, 8, 2), 256, 0, stream>>>(y5h, y5l, wp6h, wp6l, eb[5],
                                                 nullptr, nullptr, comb,
                                                 paire, pairg, b0);
  }

  t2_k<<<8320, 256, 0, stream>>>(comb, xtFh, xtFl);
  convM_k<512, 1024, 128, 2>
      <<<dim3(128, 16, 1), 256, 0, stream>>>(xtFh, xtFl, wpFh, wpFl, c2b,
                                             nullptr, nullptr, comb, nullptr,
                                             nullptr, 0);

  fc1M_k<<<dim3(4, 128), 256, 0, stream>>>(comb, f1w, part);
  fc1red_k<<<128, 256, 0, stream>>>(part, f1b, fc1o);
  fc2_k<<<128, 64, 0, stream>>>(fc1o, f2w, f2b, out);
}

// Round 12
// 645.286 us; speedup vs baseline: 1.5707x; 1.0310x over previous
//
#include <hip/hip_runtime.h>
#include <hip/hip_bf16.h>
#include <math.h>

#define B_   128
#define L_   1024
#define E_   8
#define K_   3

typedef float f32x4 __attribute__((ext_vector_type(4)));
typedef short s8v  __attribute__((ext_vector_type(8)));
typedef unsigned short u16x8 __attribute__((ext_vector_type(8)));

__device__ inline ushort f2bf(float v) {
  union { float f; unsigned u; } x; x.f = v;
  unsigned r = (x.u + 0x7fffu + ((x.u >> 16) & 1u)) >> 16;
  return (ushort)r;
}
__device__ inline float bf2f(ushort h) {
  union { unsigned u; float f; } x; x.u = ((unsigned)h) << 16;
  return x.f;
}

// async global->LDS DMA, 16B/lane; dest linear in granule index.
__device__ __forceinline__ void gload_lds16(const ushort* g, ushort* l) {
  __builtin_amdgcn_global_load_lds(
      (const __attribute__((address_space(1))) unsigned int*)g,
      (__attribute__((address_space(3))) unsigned int*)l, 16, 0, 0);
}

// ---------------------------------------------------------------------------
// conv1: x[128,1,1024] -> h[128,16,1024] (ReLU) + pooled[128,16]
// ---------------------------------------------------------------------------
__global__ __launch_bounds__(256) void conv1_k(
    const float* __restrict__ x, const float* __restrict__ w,
    const float* __restrict__ bias, float* __restrict__ h,
    float* __restrict__ pooled)
{
  const int b = blockIdx.x;
  const int t = threadIdx.x;
  __shared__ float xs[1026];
  __shared__ float wsm[48];
  __shared__ float bs[16];
  __shared__ float red[4][16];

  for (int i = t; i < 1024; i += 256) xs[i + 1] = x[(size_t)b * 1024 + i];
  if (t == 0) { xs[0] = 0.f; xs[1025] = 0.f; }
  if (t < 48) wsm[t] = w[t];
  if (t < 16) bs[t] = bias[t];
  __syncthreads();

  float ps[16];
#pragma unroll
  for (int c = 0; c < 16; ++c) ps[c] = 0.f;

  for (int li = 0; li < 4; ++li) {
    const int l = t + li * 256;
    const float xm = xs[l], x0 = xs[l + 1], xp = xs[l + 2];
#pragma unroll
    for (int co = 0; co < 16; ++co) {
      float v = fmaf(wsm[co * 3 + 0], xm,
                fmaf(wsm[co * 3 + 1], x0,
                fmaf(wsm[co * 3 + 2], xp, bs[co])));
      v = fmaxf(v, 0.f);
      h[((size_t)b * 16 + co) * 1024 + l] = v;
      ps[co] += v;
    }
  }
#pragma unroll
  for (int co = 0; co < 16; ++co) {
    float v = ps[co];
    for (int off = 32; off > 0; off >>= 1) v += __shfl_down(v, off, 64);
    ps[co] = v;
  }
  const int wid = t >> 6, lane = t & 63;
  if (lane == 0) {
#pragma unroll
    for (int co = 0; co < 16; ++co) red[wid][co] = ps[co];
  }
  __syncthreads();
  if (t < 16) pooled[(size_t)b * 16 + t] =
      (red[0][t] + red[1][t] + red[2][t] + red[3][t]) * (1.f / 1024.f);
}

// ---------------------------------------------------------------------------
// router: pooled -> top3 gates + cv^2
// ---------------------------------------------------------------------------
__global__ void router_k(const float* __restrict__ pooled,
                         const float* __restrict__ rw,
                         const float* __restrict__ rb,
                         float* __restrict__ pair_g, int* __restrict__ pair_e,
                         float* __restrict__ cv2_out)
{
  const int b = threadIdx.x;  // 0..127
  __shared__ float pl[128][8];
  __shared__ float mp[8];

  float pv[16];
#pragma unroll
  for (int i = 0; i < 16; ++i) pv[i] = pooled[(size_t)b * 16 + i];

  float lg[8];
#pragma unroll
  for (int e = 0; e < 8; ++e) {
    float s = rb[e];
#pragma unroll
    for (int i = 0; i < 16; ++i) s = fmaf(pv[i], rw[e * 16 + i], s);
    lg[e] = s;
  }
  float mx = lg[0];
#pragma unroll
  for (int e = 1; e < 8; ++e) mx = fmaxf(mx, lg[e]);
  float pr[8]; float sum = 0.f;
#pragma unroll
  for (int e = 0; e < 8; ++e) { pr[e] = expf(lg[e] - mx); sum += pr[e]; }
  const float inv = 1.f / sum;
#pragma unroll
  for (int e = 0; e < 8; ++e) { pr[e] *= inv; pl[b][e] = pr[e]; }

  bool used[8] = {false,false,false,false,false,false,false,false};
  float tg[3]; int ti[3];
  for (int k = 0; k < 3; ++k) {
    float best = -1.f; int bi = 0;
#pragma unroll
    for (int e = 0; e < 8; ++e)
      if (!used[e] && pr[e] > best) { best = pr[e]; bi = e; }
    used[bi] = true; tg[k] = best; ti[k] = bi;
  }
  const float ts = 1.f / (tg[0] + tg[1] + tg[2]);
  for (int k = 0; k < 3; ++k) {
    pair_g[b * 3 + k] = tg[k] * ts;
    pair_e[b * 3 + k] = ti[k];
  }
  __syncthreads();
  if (b < 8) {
    float s = 0.f;
    for (int i = 0; i < 128; ++i) s += pl[i][b];
    mp[b] = s * (1.f / 128.f);
  }
  __syncthreads();
  if (b == 0) {
    float m = 0.f;
    for (int e = 0; e < 8; ++e) m += mp[e];
    m *= (1.f / 8.f);
    float v = 0.f;
    for (int e = 0; e < 8; ++e) { float d = mp[e] - m; v += d * d; }
    v *= (1.f / 7.f);
    const float cv = sqrtf(v) / (m + 1e-10f);
    cv2_out[0] = cv * cv;
  }
}

// ---------------------------------------------------------------------------
// Vector conv (e1, e2 only)
// ---------------------------------------------------------------------------
template <int CI, int CO, int LIN, bool POOL, int CIC, int CO_T, int CO_R,
          int IN_DIV>
__global__ __launch_bounds__(256) void convR_k(
    const float* __restrict__ in, const float* __restrict__ w,
    const float* __restrict__ bias, float* __restrict__ out,
    const int* __restrict__ pe)
{
  constexpr int CQ  = CO_T / CO_R;
  constexpr int LQ  = 256 / CQ;
  constexpr int L_T = LQ * 4;
  constexpr int LOUT = POOL ? (LIN / 2) : LIN;
  constexpr int RS  = L_T + 8;
  constexpr int CG  = CO_R / 4;

  const int p  = blockIdx.x;
  const int cb = blockIdx.y * CO_T;
  const int l0 = blockIdx.z * L_T;
  const int e  = pe ? pe[p] : 0;
  const float* inp = in + (size_t)(p / IN_DIV) * CI * LIN;
  const float* wp  = w + (size_t)e * CO * CI * 3;

  __shared__ float in_s[CIC * RS];
  __shared__ float w_s[CIC * 3 * CO_T];

  const int t  = threadIdx.x;
  const int cq = t / LQ;
  const int lq = t % LQ;

  float acc[CO_R][4];
#pragma unroll
  for (int c = 0; c < CO_R; ++c)
#pragma unroll
    for (int l = 0; l < 4; ++l) acc[c][l] = 0.f;

  for (int c0 = 0; c0 < CI; c0 += CIC) {
    for (int idx = t; idx < CIC * (L_T + 2); idx += 256) {
      const int ci = idx / (L_T + 2);
      const int j  = idx - ci * (L_T + 2);
      const int gl = l0 + j - 1;
      in_s[ci * RS + j] =
          (gl >= 0 && gl < LIN) ? inp[(size_t)(c0 + ci) * LIN + gl] : 0.f;
    }
    for (int i = t; i < CIC * CO_T; i += 256) {
      const int co = i % CO_T;
      const int ci = i / CO_T;
      const float* wsrc = wp + ((size_t)(cb + co) * CI + (c0 + ci)) * 3;
      const float w0 = wsrc[0], w1 = wsrc[1], w2 = wsrc[2];
      w_s[(ci * 3 + 0) * CO_T + co] = w0;
      w_s[(ci * 3 + 1) * CO_T + co] = w1;
      w_s[(ci * 3 + 2) * CO_T + co] = w2;
    }
    __syncthreads();
#pragma unroll 4
    for (int ci = 0; ci < CIC; ++ci) {
      const float* row = &in_s[ci * RS + lq * 4];
      const float4 xa = *reinterpret_cast<const float4*>(row);
      const float2 xb = *reinterpret_cast<const float2*>(row + 4);
      const float xv[6] = {xa.x, xa.y, xa.z, xa.w, xb.x, xb.y};
      const float* wrow = &w_s[ci * 3 * CO_T + cq * CO_R];
#pragma unroll
      for (int k = 0; k < 3; ++k) {
#pragma unroll
        for (int cg = 0; cg < CG; ++cg) {
          const float4 wv =
              *reinterpret_cast<const float4*>(&wrow[k * CO_T + cg * 4]);
          const float wq[4] = {wv.x, wv.y, wv.z, wv.w};
#pragma unroll
          for (int c = 0; c < 4; ++c)
#pragma unroll
            for (int l = 0; l < 4; ++l)
              acc[cg * 4 + c][l] = fmaf(wq[c], xv[l + k], acc[cg * 4 + c][l]);
        }
      }
    }
    __syncthreads();
  }

#pragma unroll
  for (int c = 0; c < CO_R; ++c) {
    const int co = cb + cq * CO_R + c;
    const float bv = bias[(size_t)e * CO + co];
    const float v0 = acc[c][0] + bv, v1 = acc[c][1] + bv;
    const float v2 = acc[c][2] + bv, v3 = acc[c][3] + bv;
    float* op = out + ((size_t)p * CO + co) * LOUT;
    if (POOL) {
      const int lo = (l0 >> 1) + lq * 2;
      float2 r;
      r.x = fmaxf(fmaxf(v0, v1), 0.f);
      r.y = fmaxf(fmaxf(v2, v3), 0.f);
      *reinterpret_cast<float2*>(&op[lo]) = r;
    } else {
      const int l = l0 + lq * 4;
      *reinterpret_cast<float4*>(&op[l]) = make_float4(v0, v1, v2, v3);
    }
  }
}

// ---------------------------------------------------------------------------
// Weight prep: w fp32 [E][CO][CI][3] -> hi/lo bf16 [E][3][CI/32][CO][32]
// ---------------------------------------------------------------------------
__global__ void wprep_k(const float* __restrict__ w, ushort* __restrict__ oh,
                        ushort* __restrict__ ol, int E, int CO, int CI,
                        int total)
{
  const int idx = blockIdx.x * 256 + threadIdx.x;
  if (idx >= total) return;
  const int KC = CI >> 5;
  const int j = idx & 31;
  int r = idx >> 5;
  const int co = r % CO; r /= CO;
  const int kc = r % KC; r /= KC;
  const int tp = r % 3;
  const int e  = r / 3;
  const float v = w[(((size_t)e * CO + co) * CI + (kc * 32 + j)) * 3 + tp];
  const ushort hi = f2bf(v);
  oh[idx] = hi;
  ol[idx] = f2bf(v - bf2f(hi));
}

// ---------------------------------------------------------------------------
// t0: e2 out fp32 [P][32][512] -> xt3 hi/lo bf16 [P][514][32] (halo rows 0)
// ---------------------------------------------------------------------------
__global__ __launch_bounds__(256) void t0_k(const float* __restrict__ in,
                                            ushort* __restrict__ oh,
                                            ushort* __restrict__ ol)
{
  __shared__ float tile[32][33];
  const int p  = blockIdx.x;
  const int l0 = blockIdx.y * 32;
  const int tx = threadIdx.x & 31;
  const int ty = threadIdx.x >> 5;

#pragma unroll
  for (int i = 0; i < 4; ++i) {
    const int ci = ty + i * 8;
    tile[ci][tx] = in[(size_t)p * 16384 + (size_t)ci * 512 + l0 + tx];
  }
  __syncthreads();
#pragma unroll
  for (int i = 0; i < 4; ++i) {
    const int l = l0 + ty + i * 8;
    const float v = tile[tx][ty + i * 8];
    const size_t o = ((size_t)p * 514 + 1 + l) * 32 + tx;
    const ushort hi = f2bf(v);
    oh[o] = hi;
    ol[o] = f2bf(v - bf2f(hi));
  }
  if (blockIdx.y == 0 && threadIdx.x < 32) {
    const size_t o0 = (size_t)p * 514 * 32 + threadIdx.x;
    const size_t o1 = ((size_t)p * 514 + 513) * 32 + threadIdx.x;
    oh[o0] = 0; ol[o0] = 0; oh[o1] = 0; ol[o1] = 0;
  }
}

// ---------------------------------------------------------------------------
// MFMA conv1d (k=3, pad=1), split-bf16 (hi/lo), 16x16x32 bf16 MFMA.
// X: [NP][L+2][CI] hi/lo bf16, W: [E][3][CI/32][CO][32]; BOTH staged to LDS
// via global_load_lds (proven structure; W-from-global was a 2x loss).
// Block: 256 thr = 4 waves stacked in l. Block tile: 128 l x 64 co.
// D: col=lane&15, row=(lane>>4)*4+reg (HW-verified layout).
// OMODE 0: plain conv -> bf16 hi/lo out [NP][L+2][CO] (halo zeroed)
// OMODE 1: relu+pool; loops the 3 top-k pairs of batch (pair0+bx) INTERNALLY,
//          gacc += gate*relu(pool(conv)); writes bf16 hi/lo DIRECTLY in the
//          next conv's [B][L/2+2][CO] halo layout (t2 fused away)
// OMODE 2: relu+pool, fp32 transposed [NP][CO][L/2]
// OMODE 3: relu+pool -> bf16 hi/lo out [NP][L/2+2][CO] (halo zeroed)
// ---------------------------------------------------------------------------
template <int CI, int CO, int L, int OMODE>
__global__ __launch_bounds__(256) void convM_k(
    const ushort* __restrict__ xh, const ushort* __restrict__ xl,
    const ushort* __restrict__ wh, const ushort* __restrict__ wl,
    const float* __restrict__ bias,
    ushort* __restrict__ oh, ushort* __restrict__ ol,
    float* __restrict__ of,
    const int* __restrict__ pe, const float* __restrict__ pg,
    int pair0)
{
  constexpr int KC = CI / 32;
  constexpr int NK = (OMODE == 1) ? 3 : 1;
  const int bx = blockIdx.x;
  const int cb = blockIdx.y * 64;
  const int lz = blockIdx.z * 128;

  __shared__ ushort xs[2][130][32];
  __shared__ ushort wsm[2][3][64][32];
  ushort* xsf = &xs[0][0][0];
  ushort* wsf = &wsm[0][0][0][0];

  const int t = threadIdx.x;
  const int lane = t & 63;
  const int wv = t >> 6;
  const int l16 = lane & 15;
  const int kb8 = (lane >> 4) * 8;

  float gacc[2][4][2];
  if (OMODE == 1) {
#pragma unroll
    for (int a = 0; a < 2; ++a)
#pragma unroll
      for (int b = 0; b < 4; ++b) { gacc[a][b][0] = 0.f; gacc[a][b][1] = 0.f; }
  }

  f32x4 acc[2][4];
  int e = 0; float gate = 1.f; int lp = bx;
  float bv[4];

  for (int kp = 0; kp < NK; ++kp) {
    if (OMODE == 1) {
      const int gp = (pair0 + bx) * 3 + kp;  // pair0 = batch offset here
      e = pe[gp]; gate = pg[gp]; lp = bx * 3 + kp;
    } else if (OMODE == 2) { lp = bx; e = 0; }
    else { lp = bx; e = pe[pair0 + bx]; }

#pragma unroll
    for (int a = 0; a < 2; ++a)
#pragma unroll
      for (int b = 0; b < 4; ++b) acc[a][b] = (f32x4){0.f, 0.f, 0.f, 0.f};

    const size_t xbase = ((size_t)lp * (L + 2) + lz) * CI;

    for (int kc = 0; kc < KC; ++kc) {
      const int c0 = kc * 32;
      // X: 1040 granules (2 planes x 130 rows x 4), dest linear = xsf + g*8
#pragma unroll
      for (int it = 0; it < 5; ++it) {
        const int g = it * 256 + t;
        if (g < 1040) {
          const int pl = g >= 520;
          const int r = g - pl * 520;
          const int row = r >> 2;
          const int c16 = r & 3;
          const ushort* src =
              (pl ? xl : xh) + xbase + (size_t)row * CI + c0 + c16 * 8;
          gload_lds16(src, xsf + (size_t)g * 8);
        }
      }
      // W: 1536 granules (2 planes x 3 taps x 64 co x 4), dest = wsf + g*8
#pragma unroll
      for (int it = 0; it < 6; ++it) {
        const int g = it * 256 + t;
        const int pl = g >= 768;
        const int r = g - pl * 768;
        const int tp = r >> 8;
        const int rr = r & 255;
        const int co = rr >> 2;
        const int c16 = rr & 3;
        const ushort* src = (pl ? wl : wh) +
            ((((size_t)e * 3 + tp) * KC + kc) * CO + cb + co) * 32 + c16 * 8;
        gload_lds16(src, wsf + (size_t)g * 8);
      }
      __syncthreads();  // compiler drains vmcnt before s_barrier

      __builtin_amdgcn_s_setprio(1);
#pragma unroll
      for (int tp = 0; tp < 3; ++tp) {
        const int ar = wv * 32 + l16 + tp;
        s8v a00 = *reinterpret_cast<const s8v*>(&xs[0][ar][kb8]);
        s8v a01 = *reinterpret_cast<const s8v*>(&xs[0][ar + 16][kb8]);
        s8v a10 = *reinterpret_cast<const s8v*>(&xs[1][ar][kb8]);
        s8v a11 = *reinterpret_cast<const s8v*>(&xs[1][ar + 16][kb8]);
#pragma unroll
        for (int cs = 0; cs < 4; ++cs) {
          const int brow = cs * 16 + l16;
          s8v bh = *reinterpret_cast<const s8v*>(&wsm[0][tp][brow][kb8]);
          s8v bl = *reinterpret_cast<const s8v*>(&wsm[1][tp][brow][kb8]);
          acc[0][cs] = __builtin_amdgcn_mfma_f32_16x16x32_bf16(a00, bh, acc[0][cs], 0, 0, 0);
          acc[0][cs] = __builtin_amdgcn_mfma_f32_16x16x32_bf16(a00, bl, acc[0][cs], 0, 0, 0);
          acc[0][cs] = __builtin_amdgcn_mfma_f32_16x16x32_bf16(a10, bh, acc[0][cs], 0, 0, 0);
          acc[1][cs] = __builtin_amdgcn_mfma_f32_16x16x32_bf16(a01, bh, acc[1][cs], 0, 0, 0);
          acc[1][cs] = __builtin_amdgcn_mfma_f32_16x16x32_bf16(a01, bl, acc[1][cs], 0, 0, 0);
          acc[1][cs] = __builtin_amdgcn_mfma_f32_16x16x32_bf16(a11, bh, acc[1][cs], 0, 0, 0);
        }
      }
      __builtin_amdgcn_s_setprio(0);
      __syncthreads();
    }

#pragma unroll
    for (int cs = 0; cs < 4; ++cs)
      bv[cs] = bias[(size_t)e * CO + cb + cs * 16 + l16];

    if (OMODE == 1) {
#pragma unroll
      for (int ls = 0; ls < 2; ++ls)
#pragma unroll
        for (int cs = 0; cs < 4; ++cs)
#pragma unroll
          for (int q = 0; q < 2; ++q) {
            const float v0 = acc[ls][cs][q * 2] + bv[cs];
            const float v1 = acc[ls][cs][q * 2 + 1] + bv[cs];
            const float m = fmaxf(fmaxf(v0, v1), 0.f);
            gacc[ls][cs][q] += gate * m;
          }
    }
  }

  if (OMODE == 0) {
#pragma unroll
    for (int ls = 0; ls < 2; ++ls)
#pragma unroll
      for (int cs = 0; cs < 4; ++cs)
#pragma unroll
        for (int r = 0; r < 4; ++r) {
          const int l = lz + wv * 32 + ls * 16 + (lane >> 4) * 4 + r;
          const float v = acc[ls][cs][r] + bv[cs];
          const size_t o = ((size_t)lp * (L + 2) + 1 + l) * CO + cb + cs * 16 + l16;
          const ushort hi = f2bf(v);
          oh[o] = hi;
          ol[o] = f2bf(v - bf2f(hi));
        }
    if (blockIdx.z == 0 && t < 64) {
      const size_t o0 = (size_t)lp * (L + 2) * CO + cb + t;
      const size_t o1 = ((size_t)lp * (L + 2) + (L + 1)) * CO + cb + t;
      oh[o0] = 0; ol[o0] = 0; oh[o1] = 0; ol[o1] = 0;
    }
  } else if (OMODE == 3) {
#pragma unroll
    for (int ls = 0; ls < 2; ++ls)
#pragma unroll
      for (int cs = 0; cs < 4; ++cs)
#pragma unroll
        for (int r = 0; r < 4; r += 2) {
          const float v0 = acc[ls][cs][r] + bv[cs];
          const float v1 = acc[ls][cs][r + 1] + bv[cs];
          const float m = fmaxf(fmaxf(v0, v1), 0.f);
          const int lpp = (lz + wv * 32 + ls * 16 + (lane >> 4) * 4 + r) >> 1;
          const size_t o = ((size_t)lp * (L / 2 + 2) + 1 + lpp) * CO + cb + cs * 16 + l16;
          const ushort hi = f2bf(m);
          oh[o] = hi;
          ol[o] = f2bf(m - bf2f(hi));
        }
    if (blockIdx.z == 0 && t < 64) {
      const size_t o0 = (size_t)lp * (L / 2 + 2) * CO + cb + t;
      const size_t o1 = ((size_t)lp * (L / 2 + 2) + (L / 2 + 1)) * CO + cb + t;
      oh[o0] = 0; ol[o0] = 0; oh[o1] = 0; ol[o1] = 0;
    }
  } else if (OMODE == 1) {
    // gated sum -> bf16 hi/lo in [B][L/2+2][CO] halo layout (t2 fused)
#pragma unroll
    for (int ls = 0; ls < 2; ++ls)
#pragma unroll
      for (int cs = 0; cs < 4; ++cs)
#pragma unroll
        for (int q = 0; q < 2; ++q) {
          const int lpp = (lz + wv * 32 + ls * 16 + (lane >> 4) * 4 + q * 2) >> 1;
          const int co = cb + cs * 16 + l16;
          const size_t o =
              ((size_t)(pair0 + bx) * (L / 2 + 2) + 1 + lpp) * CO + co;
          const float g = gacc[ls][cs][q];
          const ushort hi = f2bf(g);
          oh[o] = hi;
          ol[o] = f2bf(g - bf2f(hi));
        }
    if (blockIdx.z == 0 && t < 64) {
      const size_t o0 = (size_t)(pair0 + bx) * (L / 2 + 2) * CO + cb + t;
      const size_t o1 =
          ((size_t)(pair0 + bx) * (L / 2 + 2) + (L / 2 + 1)) * CO + cb + t;
      oh[o0] = 0; ol[o0] = 0; oh[o1] = 0; ol[o1] = 0;
    }
  } else {
#pragma unroll
    for (int ls = 0; ls < 2; ++ls)
#pragma unroll
      for (int cs = 0; cs < 4; ++cs)
#pragma unroll
        for (int r = 0; r < 4; r += 2) {
          const float v0 = acc[ls][cs][r] + bv[cs];
          const float v1 = acc[ls][cs][r + 1] + bv[cs];
          const float m = fmaxf(fmaxf(v0, v1), 0.f);
          const int lpp = (lz + wv * 32 + ls * 16 + (lane >> 4) * 4 + r) >> 1;
          const int co = cb + cs * 16 + l16;
          const size_t o = ((size_t)lp * CO + co) * (L / 2) + lpp;
          of[o] = m;
        }
  }
}

// ---------------------------------------------------------------------------
// fc1 MFMA split-bf16 GEMM
// ---------------------------------------------------------------------------
__global__ __launch_bounds__(256) void fc1M_k(const float* __restrict__ X,
                                              const float* __restrict__ W,
                                              float* __restrict__ part)
{
  __shared__ ushort xs[2][128][32];
  __shared__ ushort wsm[2][64][32];
  const int t = threadIdx.x;
  const int lane = t & 63;
  const int wv = t >> 6;
  const int l16 = lane & 15;
  const int kb8 = (lane >> 4) * 8;
  const int ot = blockIdx.x * 64;
  const size_t k0g = (size_t)blockIdx.y * 512;

  f32x4 acc[2][4];
#pragma unroll
  for (int a = 0; a < 2; ++a)
#pragma unroll
    for (int b = 0; b < 4; ++b) acc[a][b] = (f32x4){0.f, 0.f, 0.f, 0.f};

  const int xrow = t >> 1;
  const int xcol = (t & 1) * 16;
  const int wco  = t >> 2;
  const int wk   = (t & 3) * 8;

  for (int it = 0; it < 16; ++it) {
    const size_t k0 = k0g + it * 32;
    {
      const float* src = X + (size_t)xrow * 65536 + k0 + xcol;
      float v[16];
#pragma unroll
      for (int q = 0; q < 4; ++q)
        *reinterpret_cast<float4*>(&v[q * 4]) =
            *reinterpret_cast<const float4*>(src + q * 4);
#pragma unroll
      for (int q = 0; q < 2; ++q) {
        u16x8 hv, lv;
#pragma unroll
        for (int j = 0; j < 8; ++j) {
          const float f = v[q * 8 + j];
          const ushort h = f2bf(f);
          hv[j] = h;
          lv[j] = f2bf(f - bf2f(h));
        }
        *reinterpret_cast<u16x8*>(&xs[0][xrow][xcol + q * 8]) = hv;
        *reinterpret_cast<u16x8*>(&xs[1][xrow][xcol + q * 8]) = lv;
      }
    }
    {
      const float* src = W + (size_t)(ot + wco) * 65536 + k0 + wk;
      float v[8];
      *reinterpret_cast<float4*>(&v[0]) = *reinterpret_cast<const float4*>(src);
      *reinterpret_cast<float4*>(&v[4]) = *reinterpret_cast<const float4*>(src + 4);
      u16x8 hv, lv;
#pragma unroll
      for (int j = 0; j < 8; ++j) {
        const ushort h = f2bf(v[j]);
        hv[j] = h;
        lv[j] = f2bf(v[j] - bf2f(h));
      }
      *reinterpret_cast<u16x8*>(&wsm[0][wco][wk]) = hv;
      *reinterpret_cast<u16x8*>(&wsm[1][wco][wk]) = lv;
    }
    __syncthreads();
    __builtin_amdgcn_s_setprio(1);
#pragma unroll
    for (int ms = 0; ms < 2; ++ms) {
      const int ar = wv * 32 + ms * 16 + l16;
      s8v ah = *reinterpret_cast<const s8v*>(&xs[0][ar][kb8]);
      s8v al = *reinterpret_cast<const s8v*>(&xs[1][ar][kb8]);
#pragma unroll
      for (int cs = 0; cs < 4; ++cs) {
        const int brow = cs * 16 + l16;
        s8v bh = *reinterpret_cast<const s8v*>(&wsm[0][brow][kb8]);
        s8v bl = *reinterpret_cast<const s8v*>(&wsm[1][brow][kb8]);
        acc[ms][cs] = __builtin_amdgcn_mfma_f32_16x16x32_bf16(ah, bh, acc[ms][cs], 0, 0, 0);
        acc[ms][cs] = __builtin_amdgcn_mfma_f32_16x16x32_bf16(ah, bl, acc[ms][cs], 0, 0, 0);
        acc[ms][cs] = __builtin_amdgcn_mfma_f32_16x16x32_bf16(al, bh, acc[ms][cs], 0, 0, 0);
      }
    }
    __builtin_amdgcn_s_setprio(0);
    __syncthreads();
  }

#pragma unroll
  for (int ms = 0; ms < 2; ++ms)
#pragma unroll
    for (int cs = 0; cs < 4; ++cs)
#pragma unroll
      for (int r = 0; r < 4; ++r) {
        const int row = wv * 32 + ms * 16 + (lane >> 4) * 4 + r;
        const int col = ot + cs * 16 + l16;
        part[((size_t)blockIdx.y * 128 + row) * 256 + col] = acc[ms][cs][r];
      }
}

__global__ void fc1red_k(const float* __restrict__ part,
                         const float* __restrict__ b1, float* __restrict__ o1)
{
  const int idx = blockIdx.x * 256 + threadIdx.x;
  if (idx < 32768) {
    float s = 0.f;
#pragma unroll 8
    for (int z = 0; z < 128; ++z) s += part[(size_t)z * 32768 + idx];
    o1[idx] = fmaxf(s + b1[idx & 255], 0.f);
  }
}

__global__ void fc2_k(const float* __restrict__ o1, const float* __restrict__ w2,
                      const float* __restrict__ b2, float* __restrict__ out)
{
  const int b = blockIdx.x;
  const int lane = threadIdx.x;
  float acc[5] = {0.f, 0.f, 0.f, 0.f, 0.f};
  for (int i = lane; i < 256; i += 64) {
    const float xv = o1[(size_t)b * 256 + i];
#pragma unroll
    for (int o = 0; o < 5; ++o) acc[o] = fmaf(xv, w2[o * 256 + i], acc[o]);
  }
#pragma unroll
  for (int o = 0; o < 5; ++o) {
    for (int off = 32; off > 0; off >>= 1)
      acc[o] += __shfl_down(acc[o], off, 64);
  }
  if (lane == 0) {
#pragma unroll
    for (int o = 0; o < 5; ++o) out[b * 5 + o] = acc[o] + b2[o];
  }
}

// ---------------------------------------------------------------------------
// launcher
// ---------------------------------------------------------------------------
extern "C" void kernel_launch(void* const* d_in, const int* in_sizes, int n_in,
                              void* d_out, int out_size, void* d_ws,
                              size_t ws_size, hipStream_t stream)
{
  const float* x   = (const float*)d_in[0];
  const float* c1w = (const float*)d_in[1];
  const float* c1b = (const float*)d_in[2];
  const float* ew[6];
  const float* eb[6];
  for (int j = 0; j < 6; ++j) {
    ew[j] = (const float*)d_in[3 + 2 * j];
    eb[j] = (const float*)d_in[4 + 2 * j];
  }
  const float* rw  = (const float*)d_in[15];
  const float* rb  = (const float*)d_in[16];
  const float* c2w = (const float*)d_in[17];
  const float* c2b = (const float*)d_in[18];
  const float* f1w = (const float*)d_in[19];
  const float* f1b = (const float*)d_in[20];
  const float* f2w = (const float*)d_in[21];
  const float* f2b = (const float*)d_in[22];
  float* out = (float*)d_out;

  // Workspace plan (chunkB=32): total ~104 MB, under the hard-proven 127 MB.
  // xtF is its own buffer (e6 writes it during chunks). comb aliases the
  // chunk slots (dead when final conv runs). part aliases xtF (dead after
  // final conv).
  const int chunkB = 32;
  const int chunkP = chunkB * 3;          // 96
  const int nchunk = 128 / chunkB;        // 4

  char* basep = (char*)d_ws;
  size_t off = 0;
  auto alloc = [&](size_t bytes) -> void* {
    off = (off + 255) & ~(size_t)255;
    void* r = basep + off;
    off += bytes;
    return r;
  };

  float* h      = (float*)alloc(2097152ull * 4);
  float* pooled = (float*)alloc(2048ull * 4);
  float* pairg  = (float*)alloc(384ull * 4);
  int*   paire  = (int*)  alloc(384ull * 4);
  float* fc1o   = (float*)alloc(32768ull * 4);

  // xtF: [128][130][512] hi/lo bf16 = 34.1 MB (part 16.8 MB aliases it later)
  ushort* xtFh  = (ushort*)alloc(8519680ull * 2 * 2);
  ushort* xtFl  = xtFh + 8519680ull;
  float*  part  = (float*)xtFh;

  // chunk ping-pong slots; comb (33.5 MB) aliases slotA+slotB (38.0 MB)
  const size_t slot_base = (off + 255) & ~(size_t)255;
  char* slotA = (char*)alloc((size_t)chunkP * 33024 * 2 * 2);  // 12.7 MB
  char* slotB = (char*)alloc((size_t)chunkP * 66048 * 2 * 2);  // 25.4 MB
  float* comb = (float*)(basep + slot_base);

  float*  bufA  = (float*)slotA;
  ushort* xt3h  = (ushort*)slotA;
  ushort* xt3l  = xt3h + (size_t)chunkP * 16448;
  ushort* xt5h  = (ushort*)slotA;
  ushort* xt5l  = xt5h + (size_t)chunkP * 33024;
  float*  bufB  = (float*)slotB;
  ushort* yE3h  = (ushort*)slotB;
  ushort* yE3l  = yE3h + (size_t)chunkP * 32896;
  ushort* y5h   = (ushort*)slotB;
  ushort* y5l   = y5h + (size_t)chunkP * 66048;

  ushort* wp3h  = (ushort*)alloc(49152ull * 2);
  ushort* wp3l  = (ushort*)alloc(49152ull * 2);
  ushort* wp4h  = (ushort*)alloc(196608ull * 2);
  ushort* wp4l  = (ushort*)alloc(196608ull * 2);
  ushort* wp5h  = (ushort*)alloc(786432ull * 2);
  ushort* wp5l  = (ushort*)alloc(786432ull * 2);
  ushort* wp6h  = (ushort*)alloc(3145728ull * 2);
  ushort* wp6l  = (ushort*)alloc(3145728ull * 2);
  ushort* wpFh  = (ushort*)alloc(1572864ull * 2);
  ushort* wpFl  = (ushort*)alloc(1572864ull * 2);

  conv1_k<<<128, 256, 0, stream>>>(x, c1w, c1b, h, pooled);
  router_k<<<1, 128, 0, stream>>>(pooled, rw, rb, pairg, paire, out + 640);

  wprep_k<<<(49152 + 255) / 256, 256, 0, stream>>>(ew[2], wp3h, wp3l, 8, 64, 32, 49152);
  wprep_k<<<(196608 + 255) / 256, 256, 0, stream>>>(ew[3], wp4h, wp4l, 8, 128, 64, 196608);
  wprep_k<<<(786432 + 255) / 256, 256, 0, stream>>>(ew[4], wp5h, wp5l, 8, 256, 128, 786432);
  wprep_k<<<(3145728 + 255) / 256, 256, 0, stream>>>(ew[5], wp6h, wp6l, 8, 512, 256, 3145728);
  wprep_k<<<(1572864 + 255) / 256, 256, 0, stream>>>(c2w, wpFh, wpFl, 1, 1024, 512, 1572864);

  for (int c = 0; c < nchunk; ++c) {
    const int b0 = c * chunkB;
    const int p0 = c * chunkP;
    convR_k<16, 16, 1024, false, 16, 16, 4, 3>
        <<<dim3(chunkP, 1, 4), 256, 0, stream>>>(
            h + (size_t)b0 * 16 * 1024, ew[0], eb[0], bufA, paire + p0);
    convR_k<16, 32, 1024, true, 16, 32, 8, 1>
        <<<dim3(chunkP, 1, 4), 256, 0, stream>>>(bufA, ew[1], eb[1], bufB,
                                                 paire + p0);
    t0_k<<<dim3(chunkP, 16), 256, 0, stream>>>(bufB, xt3h, xt3l);
    convM_k<32, 64, 512, 0>
        <<<dim3(chunkP, 1, 4), 256, 0, stream>>>(xt3h, xt3l, wp3h, wp3l, eb[2],
                                                 yE3h, yE3l, nullptr, paire,
                                                 nullptr, p0);
    convM_k<64, 128, 512, 3>
        <<<dim3(chunkP, 2, 4), 256, 0, stream>>>(yE3h, yE3l, wp4h, wp4l, eb[3],
                                                 xt5h, xt5l, nullptr, paire,
                                                 nullptr, p0);
    convM_k<128, 256, 256, 0>
        <<<dim3(chunkP, 4, 2), 256, 0, stream>>>(xt5h, xt5l, wp5h, wp5l, eb[4],
                                                 y5h, y5l, nullptr, paire,
                                                 nullptr, p0);
    // e6: 3 top-k pairs looped in-kernel, gated sum -> xtF bf16 (t2 fused)
    convM_k<256, 512, 256, 1>
        <<<dim3(chunkB, 8, 2), 256, 0, stream>>>(y5h, y5l, wp6h, wp6l, eb[5],
                                                 xtFh, xtFl, nullptr,
                                                 paire, pairg, b0);
  }

  convM_k<512, 1024, 128, 2>
      <<<dim3(128, 16, 1), 256, 0, stream>>>(xtFh, xtFl, wpFh, wpFl, c2b,
                                             nullptr, nullptr, comb, nullptr,
                                             nullptr, 0);

  fc1M_k<<<dim3(4, 128), 256, 0, stream>>>(comb, f1w, part);
  fc1red_k<<<128, 256, 0, stream>>>(part, f1b, fc1o);
  fc2_k<<<128, 64, 0, stream>>>(fc1o, f2w, f2b, out);
}